// Round 3
// baseline (320.921 us; speedup 1.0000x reference)
//
#include <hip/hip_runtime.h>

// Problem constants
#define BB 2
#define SS 2048
#define DD 2048
#define HH 16
#define HDIM 128
#define MTOK (BB*SS)     // 4096 token rows
#define BHH (BB*HH)      // 32 (b,h) pairs
#define NCHUNK 16        // scan chunks per (b,h): 2048/128
#define QKN (2*DD)       // fp8 qk row stride (q cols 0..2047, k cols 2048..4095)

typedef __attribute__((ext_vector_type(8))) __bf16 bf16x8;
typedef __attribute__((ext_vector_type(4))) float f32x4;
typedef __attribute__((ext_vector_type(8))) int i32x8;
typedef __attribute__((ext_vector_type(4))) int i32x4;

__device__ __forceinline__ unsigned short f2bf(float f) {
  unsigned u = __float_as_uint(f);
  u += 0x7FFFu + ((u >> 16) & 1u);   // RNE
  return (unsigned short)(u >> 16);
}
__device__ __forceinline__ float bf2f(unsigned short s) {
  return __uint_as_float(((unsigned)s) << 16);
}
__device__ __forceinline__ unsigned char f2e4m3(float f) {
  // HW convert, OCP e4m3fn on gfx950, saturating
  int pk = __builtin_amdgcn_cvt_pk_fp8_f32(f, f, 0, false);
  return (unsigned char)(pk & 0xFF);
}

// async global->LDS, 16B per lane; dst must be wave-uniform base (HW adds lane*16)
#define GLOAD_LDS16(src, dst)                                                   \
  __builtin_amdgcn_global_load_lds(                                             \
      (const void __attribute__((address_space(1)))*)(src),                     \
      (void __attribute__((address_space(3)))*)(dst), 16, 0, 0)

__device__ __forceinline__ void barrier_raw() {
  asm volatile("" ::: "memory");
  __builtin_amdgcn_s_barrier();
  asm volatile("" ::: "memory");
}

// ---------------- converts ----------------
// x -> bf16 (for V gemm) and fp8 (for QK gemm) in one pass
__global__ void cvt_x_dual(const float* __restrict__ in,
                           unsigned short* __restrict__ outb,
                           unsigned int* __restrict__ out8, int n4) {
  int i = blockIdx.x * blockDim.x + threadIdx.x;
  if (i < n4) {
    float4 v = ((const float4*)in)[i];
    ushort4 o;
    o.x = f2bf(v.x); o.y = f2bf(v.y); o.z = f2bf(v.z); o.w = f2bf(v.w);
    ((ushort4*)outb)[i] = o;
    int p0 = __builtin_amdgcn_cvt_pk_fp8_f32(v.x, v.y, 0, false);
    int p1 = __builtin_amdgcn_cvt_pk_fp8_f32(v.z, v.w, 0, false);
    out8[i] = (unsigned)(p0 & 0xFFFF) | ((unsigned)(p1 & 0xFFFF) << 16);
  }
}

// wq,wk -> fp8 contiguous [2*DD][DD]
__global__ void cvt_wqk8(const float* __restrict__ a, const float* __restrict__ b,
                         unsigned int* __restrict__ out) {
  int i = blockIdx.x * blockDim.x + threadIdx.x;  // < 2<<20
  int sel = i >> 20, r = i & 0xFFFFF;             // DD*DD/4 == 1<<20
  const float* src = sel == 0 ? a : b;
  float4 v = ((const float4*)src)[r];
  int p0 = __builtin_amdgcn_cvt_pk_fp8_f32(v.x, v.y, 0, false);
  int p1 = __builtin_amdgcn_cvt_pk_fp8_f32(v.z, v.w, 0, false);
  out[i] = (unsigned)(p0 & 0xFFFF) | ((unsigned)(p1 & 0xFFFF) << 16);
}

// wv,wo -> bf16, contiguous dest (wv at 0, wo at DD*DD)
__global__ void cvt_w2bf(const float* __restrict__ a, const float* __restrict__ b,
                         unsigned short* __restrict__ out) {
  int i = blockIdx.x * blockDim.x + threadIdx.x;  // < 2<<20
  int sel = i >> 20, r = i & 0xFFFFF;
  const float* src = sel == 0 ? a : b;
  float4 v = ((const float4*)src)[r];
  ushort4 o;
  o.x = f2bf(v.x); o.y = f2bf(v.y); o.z = f2bf(v.z); o.w = f2bf(v.w);
  ((ushort4*)out)[i] = o;
}

__global__ void concat2(const float* __restrict__ a, const float* __restrict__ b,
                        float* __restrict__ out) {
  int i = blockIdx.x * blockDim.x + threadIdx.x;
  if (i < DD) { out[i] = a[i]; out[DD + i] = b[i]; }
}

// ---------------- bf16 GEMM v8: C[M][N] = A[M][K] @ W[N][K]^T + bias[N] ----------
// 8-phase-class schedule (T1+T2+T3+T4+T5):
//   BM=256, BN=128, BK=64, 512 threads = 8 waves (4M x 2N), 64x64 out per wave.
//   Counted vmcnt, chunk-XOR swizzle via pre-swizzled global source, XCD remap.
template <bool OUT_BF16>
__global__ __launch_bounds__(512, 1) void gemm_bt8(
    const __bf16* __restrict__ A, const __bf16* __restrict__ W,
    const float* __restrict__ bias, void* __restrict__ Cout,
    int M, int N, int K) {
  // [buf][A: 256 rows x 128 B | B: 128 rows x 128 B] = 2 x 48 KB
  __shared__ unsigned char lds[2][49152];
  const int t = threadIdx.x;
  const int lane = t & 63, wave = t >> 6;      // wave 0..7
  const int quad = lane >> 4, l16 = lane & 15;
  const int bid = blockIdx.x;                  // 256 blocks
  const int swz = (bid & 7) * 32 + (bid >> 3); // XCD-contiguous remap (256%8==0)
  const int m0 = (swz >> 4) * 256;
  const int n0 = (swz & 15) * 128;
  const int wm = (wave >> 1) * 64;             // 0,64,128,192
  const int wn = (wave & 1) * 64;              // 0,64

  // stage sources (pre-swizzled): LDS phys chunk p of row r holds global chunk
  // p ^ (r&7).  A = rounds 0..3 (rows 0..255), B = rounds 0..1 (rows 0..127).
  const __bf16* sA[4];
#pragma unroll
  for (int c = 0; c < 4; ++c) {
    int L = c * 512 + t;
    int row = L >> 3, p = L & 7;
    sA[c] = A + (size_t)(m0 + row) * K + ((p ^ (row & 7)) * 8);
  }
  const __bf16* sB[2];
#pragma unroll
  for (int c = 0; c < 2; ++c) {
    int L = c * 512 + t;
    int row = L >> 3, p = L & 7;
    sB[c] = W + (size_t)(n0 + row) * K + ((p ^ (row & 7)) * 8);
  }
  // read-side phys chunk per (kh, quad): (kh*4 + quad) ^ (l16&7)
  const int phk0 = (quad ^ (l16 & 7)) * 16;
  const int phk1 = ((4 + quad) ^ (l16 & 7)) * 16;

  f32x4 acc[4][4] = {};

  const int NT = K >> 6;  // 64-wide K-tiles

  // prologue: stage tile 0 into buf 0 (6 loads/thread)
#pragma unroll
  for (int c = 0; c < 4; ++c)
    GLOAD_LDS16(sA[c], &lds[0][c * 8192 + wave * 1024]);
#pragma unroll
  for (int c = 0; c < 2; ++c)
    GLOAD_LDS16(sB[c], &lds[0][32768 + c * 8192 + wave * 1024]);

  for (int tt = 0; tt < NT; ++tt) {
    const int cur = tt & 1;
    const bool pf = (tt + 1 < NT);
    const int k1 = (tt + 1) << 6;

    // ---- phase 0 (k-half 0) ----
    if (pf) {
#pragma unroll
      for (int c = 0; c < 4; ++c)
        GLOAD_LDS16(sA[c] + k1, &lds[cur ^ 1][c * 8192 + wave * 1024]);
      asm volatile("s_waitcnt vmcnt(4)" ::: "memory");  // tile-t loads landed
    } else {
      asm volatile("s_waitcnt vmcnt(0)" ::: "memory");
    }
    barrier_raw();
    {
      bf16x8 af[4], bfv[4];
#pragma unroll
      for (int mt = 0; mt < 4; ++mt)
        af[mt] = *(const bf16x8*)&lds[cur][(wm + mt * 16 + l16) * 128 + phk0];
#pragma unroll
      for (int nt = 0; nt < 4; ++nt)
        bfv[nt] = *(const bf16x8*)&lds[cur][32768 + (wn + nt * 16 + l16) * 128 + phk0];
      __builtin_amdgcn_s_setprio(1);
#pragma unroll
      for (int mt = 0; mt < 4; ++mt)
#pragma unroll
        for (int nt = 0; nt < 4; ++nt)
          acc[mt][nt] = __builtin_amdgcn_mfma_f32_16x16x32_bf16(
              af[mt], bfv[nt], acc[mt][nt], 0, 0, 0);
      __builtin_amdgcn_s_setprio(0);
    }

    // ---- phase 1 (k-half 1) ----
    if (pf) {
#pragma unroll
      for (int c = 0; c < 2; ++c)
        GLOAD_LDS16(sB[c] + k1, &lds[cur ^ 1][32768 + c * 8192 + wave * 1024]);
    }
    barrier_raw();
    {
      bf16x8 af[4], bfv[4];
#pragma unroll
      for (int mt = 0; mt < 4; ++mt)
        af[mt] = *(const bf16x8*)&lds[cur][(wm + mt * 16 + l16) * 128 + phk1];
#pragma unroll
      for (int nt = 0; nt < 4; ++nt)
        bfv[nt] = *(const bf16x8*)&lds[cur][32768 + (wn + nt * 16 + l16) * 128 + phk1];
      __builtin_amdgcn_s_setprio(1);
#pragma unroll
      for (int mt = 0; mt < 4; ++mt)
#pragma unroll
        for (int nt = 0; nt < 4; ++nt)
          acc[mt][nt] = __builtin_amdgcn_mfma_f32_16x16x32_bf16(
              af[mt], bfv[nt], acc[mt][nt], 0, 0, 0);
      __builtin_amdgcn_s_setprio(0);
    }
    barrier_raw();  // all waves done reading buf[cur] before tt+1 overwrites it
  }

  // epilogue: C/D layout col=lane&15, row=quad*4+reg  [m89/m91 verified]
#pragma unroll
  for (int mt = 0; mt < 4; ++mt) {
#pragma unroll
    for (int nt = 0; nt < 4; ++nt) {
      int col = n0 + wn + nt * 16 + l16;
      float bv = bias[col];
#pragma unroll
      for (int r = 0; r < 4; ++r) {
        int row = m0 + wm + mt * 16 + quad * 4 + r;
        float v = acc[mt][nt][r] + bv;
        if constexpr (OUT_BF16)
          ((unsigned short*)Cout)[(size_t)row * N + col] = f2bf(v);
        else
          ((float*)Cout)[(size_t)row * N + col] = v;
      }
    }
  }
}

// ---------------- fp8 MX GEMM v8: C8[M][N] = e4m3( A8 @ W8^T + bias ) ------------
// Same 8-phase-class schedule as gemm_bt8 (the addressing maps 1:1 — a 128-elem
// fp8 row is 128 B = 8x16B chunks, exactly like a 64-elem bf16 row):
//   BM=256, BN=128, BK=128 (one full mfma_scale 16x16x128 K-span per tile),
//   512 threads = 8 waves (4M x 2N), 64x64 out/wave, double-buffered 96 KB LDS.
//   Phase 0: issue A-loads(t+1), vmcnt(4), barrier, A-frags + B nt{0,1}, 8 MFMA.
//   Phase 1: issue B-loads(t+1), barrier, B nt{2,3}, 8 MFMA. Trailing barrier.
//   Chunk-XOR swizzle via pre-swizzled global source; frag chunks 2q,2q+1 land
//   at phys p0, p0^1. XCD remap: 64 consecutive tiles (2 A-panels) per XCD.
__global__ __launch_bounds__(512, 1) void gemm_qk8(
    const unsigned char* __restrict__ A8, const unsigned char* __restrict__ W8,
    const float* __restrict__ bias, unsigned char* __restrict__ Cout,
    int M, int N, int K) {
  // [buf][A: 256 rows x 128 B | B: 128 rows x 128 B] = 2 x 48 KB
  __shared__ unsigned char lds[2][49152];
  const int t = threadIdx.x;
  const int lane = t & 63, wave = t >> 6;
  const int quad = lane >> 4, l16 = lane & 15;
  const int bid = blockIdx.x;                  // 512 blocks
  const int swz = (bid & 7) * 64 + (bid >> 3); // XCD-contiguous remap (512%8==0)
  const int m0 = (swz >> 5) * 256;             // 16 m-panels
  const int n0 = (swz & 31) * 128;             // 32 n-tiles
  const int wm = (wave >> 1) * 64;
  const int wn = (wave & 1) * 64;

  const unsigned char* sA[4];
#pragma unroll
  for (int c = 0; c < 4; ++c) {
    int L = c * 512 + t;
    int row = L >> 3, p = L & 7;
    sA[c] = A8 + (size_t)(m0 + row) * K + ((p ^ (row & 7)) * 16);
  }
  const unsigned char* sB[2];
#pragma unroll
  for (int c = 0; c < 2; ++c) {
    int L = c * 512 + t;
    int row = L >> 3, p = L & 7;
    sB[c] = W8 + (size_t)(n0 + row) * K + ((p ^ (row & 7)) * 16);
  }
  const int p0 = (2 * quad) ^ (l16 & 7);   // phys chunk of logical chunk 2*quad

  f32x4 acc[4][4] = {};

  const int NT = K >> 7;  // 128-wide K-tiles (16)

  // prologue: stage tile 0 into buf 0 (6 loads/thread)
#pragma unroll
  for (int c = 0; c < 4; ++c)
    GLOAD_LDS16(sA[c], &lds[0][c * 8192 + wave * 1024]);
#pragma unroll
  for (int c = 0; c < 2; ++c)
    GLOAD_LDS16(sB[c], &lds[0][32768 + c * 8192 + wave * 1024]);

  for (int tt = 0; tt < NT; ++tt) {
    const int cur = tt & 1;
    const bool pf = (tt + 1 < NT);
    const int k1 = (tt + 1) << 7;

    // ---- phase 0 ----
    if (pf) {
#pragma unroll
      for (int c = 0; c < 4; ++c)
        GLOAD_LDS16(sA[c] + k1, &lds[cur ^ 1][c * 8192 + wave * 1024]);
      asm volatile("s_waitcnt vmcnt(4)" ::: "memory");  // tile-t loads landed
    } else {
      asm volatile("s_waitcnt vmcnt(0)" ::: "memory");
    }
    barrier_raw();
    i32x8 af[4];
    {
#pragma unroll
      for (int mt = 0; mt < 4; ++mt) {
        int ra = (wm + mt * 16 + l16) * 128 + p0 * 16;
        ((i32x4*)&af[mt])[0] = *(const i32x4*)&lds[cur][ra];
        ((i32x4*)&af[mt])[1] = *(const i32x4*)&lds[cur][ra ^ 16];
      }
      i32x8 bv[2];
#pragma unroll
      for (int nt = 0; nt < 2; ++nt) {
        int rb = 32768 + (wn + nt * 16 + l16) * 128 + p0 * 16;
        ((i32x4*)&bv[nt])[0] = *(const i32x4*)&lds[cur][rb];
        ((i32x4*)&bv[nt])[1] = *(const i32x4*)&lds[cur][rb ^ 16];
      }
      __builtin_amdgcn_s_setprio(1);
#pragma unroll
      for (int mt = 0; mt < 4; ++mt)
#pragma unroll
        for (int nt = 0; nt < 2; ++nt)
          acc[mt][nt] = __builtin_amdgcn_mfma_scale_f32_16x16x128_f8f6f4(
              af[mt], bv[nt], acc[mt][nt], 0, 0, 0, 127, 0, 127);
      __builtin_amdgcn_s_setprio(0);
    }

    // ---- phase 1 ----
    if (pf) {
#pragma unroll
      for (int c = 0; c < 2; ++c)
        GLOAD_LDS16(sB[c] + k1, &lds[cur ^ 1][32768 + c * 8192 + wave * 1024]);
    }
    barrier_raw();
    {
      i32x8 bv[2];
#pragma unroll
      for (int nt = 0; nt < 2; ++nt) {
        int rb = 32768 + (wn + (nt + 2) * 16 + l16) * 128 + p0 * 16;
        ((i32x4*)&bv[nt])[0] = *(const i32x4*)&lds[cur][rb];
        ((i32x4*)&bv[nt])[1] = *(const i32x4*)&lds[cur][rb ^ 16];
      }
      __builtin_amdgcn_s_setprio(1);
#pragma unroll
      for (int mt = 0; mt < 4; ++mt)
#pragma unroll
        for (int nt = 0; nt < 2; ++nt)
          acc[mt][nt + 2] = __builtin_amdgcn_mfma_scale_f32_16x16x128_f8f6f4(
              af[mt], bv[nt], acc[mt][nt + 2], 0, 0, 0, 127, 0, 127);
      __builtin_amdgcn_s_setprio(0);
    }
    barrier_raw();  // all waves done reading buf[cur] before tt+1 overwrites it
  }

  // epilogue: C/D layout shape-determined, same as 16x16x32 [m121-m128]
#pragma unroll
  for (int mt = 0; mt < 4; ++mt) {
#pragma unroll
    for (int nt = 0; nt < 4; ++nt) {
      int col = n0 + wn + nt * 16 + l16;
      float bv = bias[col];
#pragma unroll
      for (int r = 0; r < 4; ++r) {
        int row = m0 + wm + mt * 16 + quad * 4 + r;
        Cout[(size_t)row * N + col] = f2e4m3(acc[mt][nt][r] + bv);
      }
    }
  }
}

// ---------------- QK^T upper-triangle exp row-sums + diagonal (MX fp8) ----------------
//  - one mfma_scale 16x16x128 per 16x16 score tile (K=128 = whole head-dim)
//  - waves split by COLUMN (each wave: 32 cols x all 64 rows)
//  - chunk-XOR swizzle staged via pre-swizzled global source
//  - diagonal/masked logic peeled into the first j-tile only
//  - 2-phase double-buffered staging; 2-way j-split (grid.x = 32)
__global__ __launch_bounds__(256, 4) void qk_rowsum8(
    const unsigned char* __restrict__ q8, const unsigned char* __restrict__ k8,
    float* __restrict__ denomA, float* __restrict__ denomB,
    float* __restrict__ diag) {
  __shared__ unsigned char lK[2][128 * 128];  // 32 KB double-buffered
  __shared__ float redS[4][64];
  __shared__ float redD[4][64];
  const int t = threadIdx.x;
  const int lane = t & 63, wave = t >> 6;
  const int quad = lane >> 4, l16 = lane & 15;
  const int bh = blockIdx.y;
  const int b = bh >> 4, h = bh & 15;
  const int pair = blockIdx.x >> 1;       // 0..15 (work-balanced i-tile pair)
  const int half = blockIdx.x & 1;        // j-split: tiles with k%2==half
  const float C = 0.03187935771f;         // (1/sqrt(2048)) * log2(e)
  const f32x4 fz = {0.f, 0.f, 0.f, 0.f};

  // staging source offsets (swizzled): LDS chunk L holds global chunk (L&7)^(row&7)
  int soff[4];
#pragma unroll
  for (int c = 0; c < 4; ++c) {
    int L = c * 256 + t;
    int row = L >> 3, p = L & 7;
    soff[c] = row * QKN + ((p ^ (row & 7)) * 16);
  }
  // LDS read byte offsets: B-row r = wave*32 + nt*16 + l16, phys chunk (2q)^(l16&7)
  const int p0 = (2 * quad) ^ (l16 & 7);
  int bo[2];
#pragma unroll
  for (int nt = 0; nt < 2; ++nt)
    bo[nt] = (wave * 32 + nt * 16 + l16) * 128 + p0 * 16;

  const unsigned char* kbase = k8 + (size_t)(b * SS) * QKN + h * HDIM;

  for (int sub = 0; sub < 2; ++sub) {
    const int tile = (sub == 0) ? pair : 31 - pair;
    const int i0 = tile * 64;
    const int jbase = i0 & ~127;
    const int ntile = (SS - jbase) >> 7;

    // A fragments: Q rows i0 + mt*16 + l16, k-bytes quad*32 (held in regs)
    i32x8 af[4];
    {
      const unsigned char* qbase =
          q8 + (size_t)(b * SS + i0 + l16) * QKN + h * HDIM + quad * 32;
#pragma unroll
      for (int mt = 0; mt < 4; ++mt)
        af[mt] = *(const i32x8*)(qbase + (size_t)(mt * 16) * QKN);
    }

    float rowacc[4][4] = {};

    int kidx = half;
    if (kidx < ntile) {
      {  // prologue: stage first tile into buf 0
        const unsigned char* src = kbase + (size_t)(jbase + kidx * 128) * QKN;
#pragma unroll
        for (int c = 0; c < 4; ++c)
          GLOAD_LDS16(src + soff[c], &lK[0][(c * 256 + wave * 64) * 16]);
      }
      asm volatile("s_waitcnt vmcnt(0)" ::: "memory");
      __syncthreads();
      int cur = 0;
      for (; kidx < ntile; kidx += 2, cur ^= 1) {
        if (kidx + 2 < ntile) {  // issue next-tile stage before compute
          const unsigned char* src =
              kbase + (size_t)(jbase + (kidx + 2) * 128) * QKN;
#pragma unroll
          for (int c = 0; c < 4; ++c)
            GLOAD_LDS16(src + soff[c], &lK[cur ^ 1][(c * 256 + wave * 64) * 16]);
        }
        const unsigned char* lkc = lK[cur];
        const int j0 = jbase + kidx * 128;
        if (kidx == 0) {
          // diagonal/masked tile (always half 0's first tile)
          float dloc[4][4] = {};
#pragma unroll
          for (int nt = 0; nt < 2; ++nt) {
            i32x8 bf;
            ((i32x4*)&bf)[0] = *(const i32x4*)(lkc + bo[nt]);
            ((i32x4*)&bf)[1] = *(const i32x4*)(lkc + (bo[nt] ^ 16));
            f32x4 acc[4];
#pragma unroll
            for (int mt = 0; mt < 4; ++mt)
              acc[mt] = __builtin_amdgcn_mfma_scale_f32_16x16x128_f8f6f4(
                  af[mt], bf, fz, 0, 0, 0, 127, 0, 127);
            const int colg = j0 + wave * 32 + nt * 16 + l16;
#pragma unroll
            for (int mt = 0; mt < 4; ++mt)
#pragma unroll
              for (int r = 0; r < 4; ++r) {
                int rg = i0 + mt * 16 + quad * 4 + r;
                float e = (colg >= rg)
                              ? __builtin_amdgcn_exp2f(acc[mt][r] * C) : 0.f;
                rowacc[mt][r] += e;
                if (colg == rg) dloc[mt][r] = e;
              }
          }
          // reduce + stash diag immediately (frees dloc registers)
#pragma unroll
          for (int mt = 0; mt < 4; ++mt)
#pragma unroll
            for (int r = 0; r < 4; ++r) {
              float d = dloc[mt][r];
#pragma unroll
              for (int off = 1; off < 16; off <<= 1) d += __shfl_xor(d, off, 64);
              if (l16 == 0) redD[wave][mt * 16 + quad * 4 + r] = d;
            }
        } else {
          // unmasked: all cols > all rows
#pragma unroll
          for (int nt = 0; nt < 2; ++nt) {
            i32x8 bf;
            ((i32x4*)&bf)[0] = *(const i32x4*)(lkc + bo[nt]);
            ((i32x4*)&bf)[1] = *(const i32x4*)(lkc + (bo[nt] ^ 16));
            f32x4 acc[4];
#pragma unroll
            for (int mt = 0; mt < 4; ++mt)
              acc[mt] = __builtin_amdgcn_mfma_scale_f32_16x16x128_f8f6f4(
                  af[mt], bf, fz, 0, 0, 0, 127, 0, 127);
#pragma unroll
            for (int mt = 0; mt < 4; ++mt)
#pragma unroll
              for (int r = 0; r < 4; ++r)
                rowacc[mt][r] += __builtin_amdgcn_exp2f(acc[mt][r] * C);
          }
        }
        asm volatile("s_waitcnt vmcnt(0)" ::: "memory");
        __syncthreads();
      }
    }

    // cross-wave reduction (redS/redD reused across subs -> barrier first)
    __syncthreads();
#pragma unroll
    for (int mt = 0; mt < 4; ++mt)
#pragma unroll
      for (int r = 0; r < 4; ++r) {
        float s = rowacc[mt][r];
#pragma unroll
        for (int off = 1; off < 16; off <<= 1) s += __shfl_xor(s, off, 64);
        if (l16 == 0) redS[wave][mt * 16 + quad * 4 + r] = s;
      }
    __syncthreads();
    if (t < 64) {
      const int rg = i0 + t;
      float s = redS[0][t] + redS[1][t] + redS[2][t] + redS[3][t];
      if (half == 0) {
        denomA[bh * SS + rg] = (float)rg + s;
        diag[bh * SS + rg] = redD[0][t] + redD[1][t] + redD[2][t] + redD[3][t];
      } else {
        denomB[bh * SS + rg] = s;
      }
    }
  }
}

// ---------------- V prefix-scan, two-pass, 16B/lane ----------------
// v is a dedicated [MTOK][DD] bf16 buffer.
__global__ void scan_pass1(const __bf16* __restrict__ v0,
                           float* __restrict__ csum) {
  int blk = blockIdx.x;
  int bh = blk >> 4, c = blk & 15;
  int b = bh >> 4, h = bh & 15;
  int t = threadIdx.x;
  int rs = t >> 4, dg = t & 15;
  const unsigned short* base = (const unsigned short*)v0 +
      (size_t)(b * SS + c * 128 + rs * 8) * DD + h * HDIM + dg * 8;
  float s[8] = {0.f, 0.f, 0.f, 0.f, 0.f, 0.f, 0.f, 0.f};
#pragma unroll
  for (int i = 0; i < 8; ++i) {
    uint4 u = *(const uint4*)(base + (size_t)i * DD);
    const unsigned short* us = (const unsigned short*)&u;
#pragma unroll
    for (int j = 0; j < 8; ++j) s[j] += bf2f(us[j]);
  }
  __shared__ float red[16 * 128];
#pragma unroll
  for (int j = 0; j < 8; ++j) red[rs * 128 + dg * 8 + j] = s[j];
  __syncthreads();
  for (int st = 8; st >= 1; st >>= 1) {
    if (rs < st) {
#pragma unroll
      for (int j = 0; j < 8; ++j)
        red[rs * 128 + dg * 8 + j] += red[(rs + st) * 128 + dg * 8 + j];
    }
    __syncthreads();
  }
  if (rs == 0) {
#pragma unroll
    for (int j = 0; j < 8; ++j)
      csum[(size_t)blk * 128 + dg * 8 + j] = red[dg * 8 + j];
  }
}

__global__ void scan_pass2(const __bf16* __restrict__ v0,
                           const float* __restrict__ csum,
                           const float* __restrict__ denomA,
                           const float* __restrict__ denomB,
                           const float* __restrict__ diag,
                           unsigned short* __restrict__ ctx) {
  int blk = blockIdx.x;
  int bh = blk >> 4, c = blk & 15;
  int b = bh >> 4, h = bh & 15;
  int t = threadIdx.x;
  int rs = t >> 4, dg = t & 15;
  const unsigned short* vbase = (const unsigned short*)v0 +
      (size_t)(b * SS + c * 128 + rs * 8) * DD + h * HDIM + dg * 8;
  float vrow[8][8];
  float ls[8] = {0.f, 0.f, 0.f, 0.f, 0.f, 0.f, 0.f, 0.f};
#pragma unroll
  for (int i = 0; i < 8; ++i) {
    uint4 u = *(const uint4*)(vbase + (size_t)i * DD);
    const unsigned short* us = (const unsigned short*)&u;
#pragma unroll
    for (int j = 0; j < 8; ++j) {
      vrow[i][j] = bf2f(us[j]);
      ls[j] += vrow[i][j];
    }
  }
  __shared__ float red[16 * 128];
#pragma unroll
  for (int j = 0; j < 8; ++j) red[rs * 128 + dg * 8 + j] = ls[j];
  __syncthreads();

  float pre[8] = {0.f, 0.f, 0.f, 0.f, 0.f, 0.f, 0.f, 0.f};
  for (int cc = 0; cc < c; ++cc) {
    const float* cp = csum + (size_t)(bh * 16 + cc) * 128 + dg * 8;
#pragma unroll
    for (int j = 0; j < 8; ++j) pre[j] += cp[j];
  }
  for (int ss2 = 0; ss2 < rs; ++ss2) {
#pragma unroll
    for (int j = 0; j < 8; ++j) pre[j] += red[ss2 * 128 + dg * 8 + j];
  }

  int row0 = c * 128 + rs * 8;
  unsigned short* obase =
      ctx + (size_t)(b * SS + row0) * DD + h * HDIM + dg * 8;
  const float* dnA = denomA + bh * SS + row0;
  const float* dnB = denomB + bh * SS + row0;
  const float* dgp = diag + bh * SS + row0;
#pragma unroll
  for (int i = 0; i < 8; ++i) {
    float inv = 1.0f / (dnA[i] + dnB[i]);
    float dv = dgp[i];
    unsigned short o[8];
#pragma unroll
    for (int j = 0; j < 8; ++j) {
      float val = (pre[j] + dv * vrow[i][j]) * inv;
      o[j] = f2bf(val);
      pre[j] += vrow[i][j];
    }
    *(uint4*)(obase + (size_t)i * DD) = *(const uint4*)o;
  }
}

extern "C" void kernel_launch(void* const* d_in, const int* in_sizes, int n_in,
                              void* d_out, int out_size, void* d_ws, size_t ws_size,
                              hipStream_t stream) {
  (void)in_sizes; (void)n_in; (void)out_size; (void)ws_size;
  const float* x    = (const float*)d_in[0];
  const float* wq_w = (const float*)d_in[1];
  const float* wq_b = (const float*)d_in[2];
  const float* wk_w = (const float*)d_in[3];
  const float* wk_b = (const float*)d_in[4];
  const float* wv_w = (const float*)d_in[5];
  const float* wv_b = (const float*)d_in[6];
  const float* wo_w = (const float*)d_in[7];
  const float* wo_b = (const float*)d_in[8];

  char* ws = (char*)d_ws;
  size_t off = 0;
  auto alloc = [&](size_t bytes) {
    char* p = ws + off;
    off += (bytes + 255) & ~(size_t)255;
    return p;
  };
  unsigned short* xb   = (unsigned short*)alloc((size_t)MTOK * DD * 2);    // 16 MB
  unsigned char*  x8   = (unsigned char*)alloc((size_t)MTOK * DD);         // 8 MB
  unsigned char*  wqk8 = (unsigned char*)alloc((size_t)2 * DD * DD);       // 8 MB
  unsigned short* wvo  = (unsigned short*)alloc((size_t)2 * DD * DD * 2);  // 16 MB (wv | wo)
  unsigned char*  qk8  = (unsigned char*)alloc((size_t)MTOK * QKN);        // 16 MB
  unsigned short* v    = (unsigned short*)alloc((size_t)MTOK * DD * 2);    // 16 MB
  unsigned short* ctx  = (unsigned short*)alloc((size_t)MTOK * DD * 2);    // 16 MB
  float* biasqk = (float*)alloc((size_t)2 * DD * 4);
  float* denomA = (float*)alloc((size_t)BHH * SS * 4);
  float* denomB = (float*)alloc((size_t)BHH * SS * 4);
  float* diag   = (float*)alloc((size_t)BHH * SS * 4);
  float* csum   = (float*)alloc((size_t)BHH * NCHUNK * 128 * 4);

  // 1) converts
  {
    int n4 = MTOK * DD / 4;
    cvt_x_dual<<<n4 / 256, 256, 0, stream>>>(x, xb, (unsigned int*)x8, n4);
    cvt_wqk8<<<(2 << 20) / 256, 256, 0, stream>>>(wq_w, wk_w, (unsigned int*)wqk8);
    cvt_w2bf<<<(2 << 20) / 256, 256, 0, stream>>>(wv_w, wo_w, wvo);
    concat2<<<(DD + 255) / 256, 256, 0, stream>>>(wq_b, wk_b, biasqk);
  }

  // 2) QK projection, MX-fp8 (8-phase-class): [4096,2048] x [4096,2048]^T -> qk8
  gemm_qk8<<<(MTOK / 256) * (QKN / 128), 512, 0, stream>>>(
      x8, wqk8, biasqk, qk8, MTOK, QKN, DD);

  // 3) V projection in bf16 -> v [4096][2048]  (8-phase GEMM, BM=256 BN=128)
  gemm_bt8<true><<<(MTOK / 256) * (DD / 128), 512, 0, stream>>>(
      (const __bf16*)xb, (const __bf16*)wvo, wv_b, v, MTOK, DD, DD);

  // 4) denominators + diagonal exps (MX fp8 MFMA, paired i-tiles, 2-way j-split)
  qk_rowsum8<<<dim3(32, BHH), 256, 0, stream>>>(
      qk8,            // q at col 0
      qk8 + DD,       // k at col 2048
      denomA, denomB, diag);

  // 5) V scan -> ctx
  scan_pass1<<<BHH * NCHUNK, 256, 0, stream>>>((const __bf16*)v, csum);
  scan_pass2<<<BHH * NCHUNK, 256, 0, stream>>>((const __bf16*)v, csum,
                                               denomA, denomB, diag, ctx);

  // 6) output projection: [4096,2048] x [2048,2048]^T -> d_out fp32
  gemm_bt8<false><<<(MTOK / 256) * (DD / 128), 512, 0, stream>>>(
      (const __bf16*)ctx, (const __bf16*)(wvo + (size_t)DD * DD), wo_b,
      d_out, MTOK, DD, DD);
}

// Round 6
// 320.048 us; speedup vs baseline: 1.0027x; 1.0027x over previous
//
#include <hip/hip_runtime.h>

// Problem constants
#define BB 2
#define SS 2048
#define DD 2048
#define HH 16
#define HDIM 128
#define MTOK (BB*SS)     // 4096 token rows
#define BHH (BB*HH)      // 32 (b,h) pairs
#define NCHUNK 16        // scan chunks per (b,h): 2048/128
#define QKN (2*DD)       // fp8 qk row stride (q cols 0..2047, k cols 2048..4095)

typedef __attribute__((ext_vector_type(8))) __bf16 bf16x8;
typedef __attribute__((ext_vector_type(4))) float f32x4;
typedef __attribute__((ext_vector_type(8))) int i32x8;
typedef __attribute__((ext_vector_type(4))) int i32x4;

__device__ __forceinline__ unsigned short f2bf(float f) {
  unsigned u = __float_as_uint(f);
  u += 0x7FFFu + ((u >> 16) & 1u);   // RNE
  return (unsigned short)(u >> 16);
}
__device__ __forceinline__ float bf2f(unsigned short s) {
  return __uint_as_float(((unsigned)s) << 16);
}
__device__ __forceinline__ unsigned char f2e4m3(float f) {
  // HW convert, OCP e4m3fn on gfx950, saturating
  int pk = __builtin_amdgcn_cvt_pk_fp8_f32(f, f, 0, false);
  return (unsigned char)(pk & 0xFF);
}

// async global->LDS, 16B per lane; dst must be wave-uniform base (HW adds lane*16)
#define GLOAD_LDS16(src, dst)                                                   \
  __builtin_amdgcn_global_load_lds(                                             \
      (const void __attribute__((address_space(1)))*)(src),                     \
      (void __attribute__((address_space(3)))*)(dst), 16, 0, 0)

__device__ __forceinline__ void barrier_raw() {
  asm volatile("" ::: "memory");
  __builtin_amdgcn_s_barrier();
  asm volatile("" ::: "memory");
}

// ---------------- converts ----------------
// x -> bf16 (for V gemm) and fp8 (for QK gemm) in one pass
__global__ void cvt_x_dual(const float* __restrict__ in,
                           unsigned short* __restrict__ outb,
                           unsigned int* __restrict__ out8, int n4) {
  int i = blockIdx.x * blockDim.x + threadIdx.x;
  if (i < n4) {
    float4 v = ((const float4*)in)[i];
    ushort4 o;
    o.x = f2bf(v.x); o.y = f2bf(v.y); o.z = f2bf(v.z); o.w = f2bf(v.w);
    ((ushort4*)outb)[i] = o;
    int p0 = __builtin_amdgcn_cvt_pk_fp8_f32(v.x, v.y, 0, false);
    int p1 = __builtin_amdgcn_cvt_pk_fp8_f32(v.z, v.w, 0, false);
    out8[i] = (unsigned)(p0 & 0xFFFF) | ((unsigned)(p1 & 0xFFFF) << 16);
  }
}

// wq,wk -> fp8 contiguous [2*DD][DD]
__global__ void cvt_wqk8(const float* __restrict__ a, const float* __restrict__ b,
                         unsigned int* __restrict__ out) {
  int i = blockIdx.x * blockDim.x + threadIdx.x;  // < 2<<20
  int sel = i >> 20, r = i & 0xFFFFF;             // DD*DD/4 == 1<<20
  const float* src = sel == 0 ? a : b;
  float4 v = ((const float4*)src)[r];
  int p0 = __builtin_amdgcn_cvt_pk_fp8_f32(v.x, v.y, 0, false);
  int p1 = __builtin_amdgcn_cvt_pk_fp8_f32(v.z, v.w, 0, false);
  out[i] = (unsigned)(p0 & 0xFFFF) | ((unsigned)(p1 & 0xFFFF) << 16);
}

// wv,wo -> bf16, contiguous dest (wv at 0, wo at DD*DD)
__global__ void cvt_w2bf(const float* __restrict__ a, const float* __restrict__ b,
                         unsigned short* __restrict__ out) {
  int i = blockIdx.x * blockDim.x + threadIdx.x;  // < 2<<20
  int sel = i >> 20, r = i & 0xFFFFF;
  const float* src = sel == 0 ? a : b;
  float4 v = ((const float4*)src)[r];
  ushort4 o;
  o.x = f2bf(v.x); o.y = f2bf(v.y); o.z = f2bf(v.z); o.w = f2bf(v.w);
  ((ushort4*)out)[i] = o;
}

__global__ void concat2(const float* __restrict__ a, const float* __restrict__ b,
                        float* __restrict__ out) {
  int i = blockIdx.x * blockDim.x + threadIdx.x;
  if (i < DD) { out[i] = a[i]; out[DD + i] = b[i]; }
}

// ---------------- bf16 GEMM v8: C[M][N] = A[M][K] @ W[N][K]^T + bias[N] ----------
// 8-phase-class schedule (T1+T2+T3+T4+T5):
//   BM=256, BN=128, BK=64, 512 threads = 8 waves (4M x 2N), 64x64 out per wave.
//   Counted vmcnt, chunk-XOR swizzle via pre-swizzled global source, XCD remap
//   (m-contiguous per XCD: all 32 blocks/XCD co-resident, ws = 2 MB A + 8 MB B).
template <bool OUT_BF16>
__global__ __launch_bounds__(512, 1) void gemm_bt8(
    const __bf16* __restrict__ A, const __bf16* __restrict__ W,
    const float* __restrict__ bias, void* __restrict__ Cout,
    int M, int N, int K) {
  // [buf][A: 256 rows x 128 B | B: 128 rows x 128 B] = 2 x 48 KB
  __shared__ unsigned char lds[2][49152];
  const int t = threadIdx.x;
  const int lane = t & 63, wave = t >> 6;      // wave 0..7
  const int quad = lane >> 4, l16 = lane & 15;
  const int bid = blockIdx.x;                  // 256 blocks
  const int swz = (bid & 7) * 32 + (bid >> 3); // XCD-contiguous remap (256%8==0)
  const int m0 = (swz >> 4) * 256;
  const int n0 = (swz & 15) * 128;
  const int wm = (wave >> 1) * 64;             // 0,64,128,192
  const int wn = (wave & 1) * 64;              // 0,64

  // stage sources (pre-swizzled): LDS phys chunk p of row r holds global chunk
  // p ^ (r&7).  A = rounds 0..3 (rows 0..255), B = rounds 0..1 (rows 0..127).
  const __bf16* sA[4];
#pragma unroll
  for (int c = 0; c < 4; ++c) {
    int L = c * 512 + t;
    int row = L >> 3, p = L & 7;
    sA[c] = A + (size_t)(m0 + row) * K + ((p ^ (row & 7)) * 8);
  }
  const __bf16* sB[2];
#pragma unroll
  for (int c = 0; c < 2; ++c) {
    int L = c * 512 + t;
    int row = L >> 3, p = L & 7;
    sB[c] = W + (size_t)(n0 + row) * K + ((p ^ (row & 7)) * 8);
  }
  // read-side phys chunk per (kh, quad): (kh*4 + quad) ^ (l16&7)
  const int phk0 = (quad ^ (l16 & 7)) * 16;
  const int phk1 = ((4 + quad) ^ (l16 & 7)) * 16;

  f32x4 acc[4][4] = {};

  const int NT = K >> 6;  // 64-wide K-tiles

  // prologue: stage tile 0 into buf 0 (6 loads/thread)
#pragma unroll
  for (int c = 0; c < 4; ++c)
    GLOAD_LDS16(sA[c], &lds[0][c * 8192 + wave * 1024]);
#pragma unroll
  for (int c = 0; c < 2; ++c)
    GLOAD_LDS16(sB[c], &lds[0][32768 + c * 8192 + wave * 1024]);

  for (int tt = 0; tt < NT; ++tt) {
    const int cur = tt & 1;
    const bool pf = (tt + 1 < NT);
    const int k1 = (tt + 1) << 6;

    // ---- phase 0 (k-half 0) ----
    if (pf) {
#pragma unroll
      for (int c = 0; c < 4; ++c)
        GLOAD_LDS16(sA[c] + k1, &lds[cur ^ 1][c * 8192 + wave * 1024]);
      asm volatile("s_waitcnt vmcnt(4)" ::: "memory");  // tile-t loads landed
    } else {
      asm volatile("s_waitcnt vmcnt(0)" ::: "memory");
    }
    barrier_raw();
    {
      bf16x8 af[4], bfv[4];
#pragma unroll
      for (int mt = 0; mt < 4; ++mt)
        af[mt] = *(const bf16x8*)&lds[cur][(wm + mt * 16 + l16) * 128 + phk0];
#pragma unroll
      for (int nt = 0; nt < 4; ++nt)
        bfv[nt] = *(const bf16x8*)&lds[cur][32768 + (wn + nt * 16 + l16) * 128 + phk0];
      __builtin_amdgcn_s_setprio(1);
#pragma unroll
      for (int mt = 0; mt < 4; ++mt)
#pragma unroll
        for (int nt = 0; nt < 4; ++nt)
          acc[mt][nt] = __builtin_amdgcn_mfma_f32_16x16x32_bf16(
              af[mt], bfv[nt], acc[mt][nt], 0, 0, 0);
      __builtin_amdgcn_s_setprio(0);
    }

    // ---- phase 1 (k-half 1) ----
    if (pf) {
#pragma unroll
      for (int c = 0; c < 2; ++c)
        GLOAD_LDS16(sB[c] + k1, &lds[cur ^ 1][32768 + c * 8192 + wave * 1024]);
    }
    barrier_raw();
    {
      bf16x8 af[4], bfv[4];
#pragma unroll
      for (int mt = 0; mt < 4; ++mt)
        af[mt] = *(const bf16x8*)&lds[cur][(wm + mt * 16 + l16) * 128 + phk1];
#pragma unroll
      for (int nt = 0; nt < 4; ++nt)
        bfv[nt] = *(const bf16x8*)&lds[cur][32768 + (wn + nt * 16 + l16) * 128 + phk1];
      __builtin_amdgcn_s_setprio(1);
#pragma unroll
      for (int mt = 0; mt < 4; ++mt)
#pragma unroll
        for (int nt = 0; nt < 4; ++nt)
          acc[mt][nt] = __builtin_amdgcn_mfma_f32_16x16x32_bf16(
              af[mt], bfv[nt], acc[mt][nt], 0, 0, 0);
      __builtin_amdgcn_s_setprio(0);
    }
    barrier_raw();  // all waves done reading buf[cur] before tt+1 overwrites it
  }

  // epilogue: C/D layout col=lane&15, row=quad*4+reg  [m89/m91 verified]
#pragma unroll
  for (int mt = 0; mt < 4; ++mt) {
#pragma unroll
    for (int nt = 0; nt < 4; ++nt) {
      int col = n0 + wn + nt * 16 + l16;
      float bv = bias[col];
#pragma unroll
      for (int r = 0; r < 4; ++r) {
        int row = m0 + wm + mt * 16 + quad * 4 + r;
        float v = acc[mt][nt][r] + bv;
        if constexpr (OUT_BF16)
          ((unsigned short*)Cout)[(size_t)row * N + col] = f2bf(v);
        else
          ((float*)Cout)[(size_t)row * N + col] = v;
      }
    }
  }
}

// ---------------- fp8 MX GEMM v9: C8[M][N] = e4m3( A8 @ W8^T + bias ) ------------
// Same counted-vmcnt schedule as gemm_bt8; BM=256, BN=128, BK=128.
// Block mapping: natural 2D grid (round-3 post-mortem): x = n-tile fastest ->
// XCD ~ n%8 -> per-XCD B working set = 4 panels = 1 MB (L2-resident), rolling
// A window ~2-4 MB. The m-contiguous remap put all 8 MB of W8 on every XCD
// (FETCH 40 -> 70 MB, MfmaUtil -2.7, dur +2.5 us).
__global__ __launch_bounds__(512, 1) void gemm_qk8(
    const unsigned char* __restrict__ A8, const unsigned char* __restrict__ W8,
    const float* __restrict__ bias, unsigned char* __restrict__ Cout,
    int M, int N, int K) {
  // [buf][A: 256 rows x 128 B | B: 128 rows x 128 B] = 2 x 48 KB
  __shared__ unsigned char lds[2][49152];
  const int t = threadIdx.x;
  const int lane = t & 63, wave = t >> 6;
  const int quad = lane >> 4, l16 = lane & 15;
  const int m0 = blockIdx.y * 256;             // 16 m-panels
  const int n0 = blockIdx.x * 128;             // 32 n-tiles (fastest -> XCD=n%8)
  const int wm = (wave >> 1) * 64;
  const int wn = (wave & 1) * 64;

  const unsigned char* sA[4];
#pragma unroll
  for (int c = 0; c < 4; ++c) {
    int L = c * 512 + t;
    int row = L >> 3, p = L & 7;
    sA[c] = A8 + (size_t)(m0 + row) * K + ((p ^ (row & 7)) * 16);
  }
  const unsigned char* sB[2];
#pragma unroll
  for (int c = 0; c < 2; ++c) {
    int L = c * 512 + t;
    int row = L >> 3, p = L & 7;
    sB[c] = W8 + (size_t)(n0 + row) * K + ((p ^ (row & 7)) * 16);
  }
  const int p0 = (2 * quad) ^ (l16 & 7);   // phys chunk of logical chunk 2*quad

  f32x4 acc[4][4] = {};

  const int NT = K >> 7;  // 128-wide K-tiles (16)

  // prologue: stage tile 0 into buf 0 (6 loads/thread)
#pragma unroll
  for (int c = 0; c < 4; ++c)
    GLOAD_LDS16(sA[c], &lds[0][c * 8192 + wave * 1024]);
#pragma unroll
  for (int c = 0; c < 2; ++c)
    GLOAD_LDS16(sB[c], &lds[0][32768 + c * 8192 + wave * 1024]);

  for (int tt = 0; tt < NT; ++tt) {
    const int cur = tt & 1;
    const bool pf = (tt + 1 < NT);
    const int k1 = (tt + 1) << 7;

    // ---- phase 0 ----
    if (pf) {
#pragma unroll
      for (int c = 0; c < 4; ++c)
        GLOAD_LDS16(sA[c] + k1, &lds[cur ^ 1][c * 8192 + wave * 1024]);
      asm volatile("s_waitcnt vmcnt(4)" ::: "memory");  // tile-t loads landed
    } else {
      asm volatile("s_waitcnt vmcnt(0)" ::: "memory");
    }
    barrier_raw();
    i32x8 af[4];
    {
#pragma unroll
      for (int mt = 0; mt < 4; ++mt) {
        int ra = (wm + mt * 16 + l16) * 128 + p0 * 16;
        ((i32x4*)&af[mt])[0] = *(const i32x4*)&lds[cur][ra];
        ((i32x4*)&af[mt])[1] = *(const i32x4*)&lds[cur][ra ^ 16];
      }
      i32x8 bv[2];
#pragma unroll
      for (int nt = 0; nt < 2; ++nt) {
        int rb = 32768 + (wn + nt * 16 + l16) * 128 + p0 * 16;
        ((i32x4*)&bv[nt])[0] = *(const i32x4*)&lds[cur][rb];
        ((i32x4*)&bv[nt])[1] = *(const i32x4*)&lds[cur][rb ^ 16];
      }
      __builtin_amdgcn_s_setprio(1);
#pragma unroll
      for (int mt = 0; mt < 4; ++mt)
#pragma unroll
        for (int nt = 0; nt < 2; ++nt)
          acc[mt][nt] = __builtin_amdgcn_mfma_scale_f32_16x16x128_f8f6f4(
              af[mt], bv[nt], acc[mt][nt], 0, 0, 0, 127, 0, 127);
      __builtin_amdgcn_s_setprio(0);
    }

    // ---- phase 1 ----
    if (pf) {
#pragma unroll
      for (int c = 0; c < 2; ++c)
        GLOAD_LDS16(sB[c] + k1, &lds[cur ^ 1][32768 + c * 8192 + wave * 1024]);
    }
    barrier_raw();
    {
      i32x8 bv[2];
#pragma unroll
      for (int nt = 0; nt < 2; ++nt) {
        int rb = 32768 + (wn + (nt + 2) * 16 + l16) * 128 + p0 * 16;
        ((i32x4*)&bv[nt])[0] = *(const i32x4*)&lds[cur][rb];
        ((i32x4*)&bv[nt])[1] = *(const i32x4*)&lds[cur][rb ^ 16];
      }
      __builtin_amdgcn_s_setprio(1);
#pragma unroll
      for (int mt = 0; mt < 4; ++mt)
#pragma unroll
        for (int nt = 0; nt < 2; ++nt)
          acc[mt][nt + 2] = __builtin_amdgcn_mfma_scale_f32_16x16x128_f8f6f4(
              af[mt], bv[nt], acc[mt][nt + 2], 0, 0, 0, 127, 0, 127);
      __builtin_amdgcn_s_setprio(0);
    }
    barrier_raw();  // all waves done reading buf[cur] before tt+1 overwrites it
  }

  // epilogue: C/D layout shape-determined, same as 16x16x32 [m121-m128]
#pragma unroll
  for (int mt = 0; mt < 4; ++mt) {
#pragma unroll
    for (int nt = 0; nt < 4; ++nt) {
      int col = n0 + wn + nt * 16 + l16;
      float bv = bias[col];
#pragma unroll
      for (int r = 0; r < 4; ++r) {
        int row = m0 + wm + mt * 16 + quad * 4 + r;
        Cout[(size_t)row * N + col] = f2e4m3(acc[mt][nt][r] + bv);
      }
    }
  }
}

// ---------------- QK^T upper-triangle exp row-sums + diagonal (MX fp8) ----------------
//  - one mfma_scale 16x16x128 per 16x16 score tile (K=128 = whole head-dim)
//  - waves split by COLUMN (each wave: 32 cols x all 64 rows)
//  - chunk-XOR swizzle staged via pre-swizzled global source
//  - diagonal/masked logic peeled into the first j-tile only
//  - 2-phase double-buffered staging; 2-way j-split (grid.x = 32)
__global__ __launch_bounds__(256, 4) void qk_rowsum8(
    const unsigned char* __restrict__ q8, const unsigned char* __restrict__ k8,
    float* __restrict__ denomA, float* __restrict__ denomB,
    float* __restrict__ diag) {
  __shared__ unsigned char lK[2][128 * 128];  // 32 KB double-buffered
  __shared__ float redS[4][64];
  __shared__ float redD[4][64];
  const int t = threadIdx.x;
  const int lane = t & 63, wave = t >> 6;
  const int quad = lane >> 4, l16 = lane & 15;
  const int bh = blockIdx.y;
  const int b = bh >> 4, h = bh & 15;
  const int pair = blockIdx.x >> 1;       // 0..15 (work-balanced i-tile pair)
  const int half = blockIdx.x & 1;        // j-split: tiles with k%2==half
  const float C = 0.03187935771f;         // (1/sqrt(2048)) * log2(e)
  const f32x4 fz = {0.f, 0.f, 0.f, 0.f};

  // staging source offsets (swizzled): LDS chunk L holds global chunk (L&7)^(row&7)
  int soff[4];
#pragma unroll
  for (int c = 0; c < 4; ++c) {
    int L = c * 256 + t;
    int row = L >> 3, p = L & 7;
    soff[c] = row * QKN + ((p ^ (row & 7)) * 16);
  }
  // LDS read byte offsets: B-row r = wave*32 + nt*16 + l16, phys chunk (2q)^(l16&7)
  const int p0 = (2 * quad) ^ (l16 & 7);
  int bo[2];
#pragma unroll
  for (int nt = 0; nt < 2; ++nt)
    bo[nt] = (wave * 32 + nt * 16 + l16) * 128 + p0 * 16;

  const unsigned char* kbase = k8 + (size_t)(b * SS) * QKN + h * HDIM;

  for (int sub = 0; sub < 2; ++sub) {
    const int tile = (sub == 0) ? pair : 31 - pair;
    const int i0 = tile * 64;
    const int jbase = i0 & ~127;
    const int ntile = (SS - jbase) >> 7;

    // A fragments: Q rows i0 + mt*16 + l16, k-bytes quad*32 (held in regs)
    i32x8 af[4];
    {
      const unsigned char* qbase =
          q8 + (size_t)(b * SS + i0 + l16) * QKN + h * HDIM + quad * 32;
#pragma unroll
      for (int mt = 0; mt < 4; ++mt)
        af[mt] = *(const i32x8*)(qbase + (size_t)(mt * 16) * QKN);
    }

    float rowacc[4][4] = {};

    int kidx = half;
    if (kidx < ntile) {
      {  // prologue: stage first tile into buf 0
        const unsigned char* src = kbase + (size_t)(jbase + kidx * 128) * QKN;
#pragma unroll
        for (int c = 0; c < 4; ++c)
          GLOAD_LDS16(src + soff[c], &lK[0][(c * 256 + wave * 64) * 16]);
      }
      asm volatile("s_waitcnt vmcnt(0)" ::: "memory");
      __syncthreads();
      int cur = 0;
      for (; kidx < ntile; kidx += 2, cur ^= 1) {
        if (kidx + 2 < ntile) {  // issue next-tile stage before compute
          const unsigned char* src =
              kbase + (size_t)(jbase + (kidx + 2) * 128) * QKN;
#pragma unroll
          for (int c = 0; c < 4; ++c)
            GLOAD_LDS16(src + soff[c], &lK[cur ^ 1][(c * 256 + wave * 64) * 16]);
        }
        const unsigned char* lkc = lK[cur];
        const int j0 = jbase + kidx * 128;
        if (kidx == 0) {
          // diagonal/masked tile (always half 0's first tile)
          float dloc[4][4] = {};
#pragma unroll
          for (int nt = 0; nt < 2; ++nt) {
            i32x8 bf;
            ((i32x4*)&bf)[0] = *(const i32x4*)(lkc + bo[nt]);
            ((i32x4*)&bf)[1] = *(const i32x4*)(lkc + (bo[nt] ^ 16));
            f32x4 acc[4];
#pragma unroll
            for (int mt = 0; mt < 4; ++mt)
              acc[mt] = __builtin_amdgcn_mfma_scale_f32_16x16x128_f8f6f4(
                  af[mt], bf, fz, 0, 0, 0, 127, 0, 127);
            const int colg = j0 + wave * 32 + nt * 16 + l16;
#pragma unroll
            for (int mt = 0; mt < 4; ++mt)
#pragma unroll
              for (int r = 0; r < 4; ++r) {
                int rg = i0 + mt * 16 + quad * 4 + r;
                float e = (colg >= rg)
                              ? __builtin_amdgcn_exp2f(acc[mt][r] * C) : 0.f;
                rowacc[mt][r] += e;
                if (colg == rg) dloc[mt][r] = e;
              }
          }
          // reduce + stash diag immediately (frees dloc registers)
#pragma unroll
          for (int mt = 0; mt < 4; ++mt)
#pragma unroll
            for (int r = 0; r < 4; ++r) {
              float d = dloc[mt][r];
#pragma unroll
              for (int off = 1; off < 16; off <<= 1) d += __shfl_xor(d, off, 64);
              if (l16 == 0) redD[wave][mt * 16 + quad * 4 + r] = d;
            }
        } else {
          // unmasked: all cols > all rows
#pragma unroll
          for (int nt = 0; nt < 2; ++nt) {
            i32x8 bf;
            ((i32x4*)&bf)[0] = *(const i32x4*)(lkc + bo[nt]);
            ((i32x4*)&bf)[1] = *(const i32x4*)(lkc + (bo[nt] ^ 16));
            f32x4 acc[4];
#pragma unroll
            for (int mt = 0; mt < 4; ++mt)
              acc[mt] = __builtin_amdgcn_mfma_scale_f32_16x16x128_f8f6f4(
                  af[mt], bf, fz, 0, 0, 0, 127, 0, 127);
#pragma unroll
            for (int mt = 0; mt < 4; ++mt)
#pragma unroll
              for (int r = 0; r < 4; ++r)
                rowacc[mt][r] += __builtin_amdgcn_exp2f(acc[mt][r] * C);
          }
        }
        asm volatile("s_waitcnt vmcnt(0)" ::: "memory");
        __syncthreads();
      }
    }

    // cross-wave reduction (redS/redD reused across subs -> barrier first)
    __syncthreads();
#pragma unroll
    for (int mt = 0; mt < 4; ++mt)
#pragma unroll
      for (int r = 0; r < 4; ++r) {
        float s = rowacc[mt][r];
#pragma unroll
        for (int off = 1; off < 16; off <<= 1) s += __shfl_xor(s, off, 64);
        if (l16 == 0) redS[wave][mt * 16 + quad * 4 + r] = s;
      }
    __syncthreads();
    if (t < 64) {
      const int rg = i0 + t;
      float s = redS[0][t] + redS[1][t] + redS[2][t] + redS[3][t];
      if (half == 0) {
        denomA[bh * SS + rg] = (float)rg + s;
        diag[bh * SS + rg] = redD[0][t] + redD[1][t] + redD[2][t] + redD[3][t];
      } else {
        denomB[bh * SS + rg] = s;
      }
    }
  }
}

// ---------------- V prefix-scan, two-pass, 16B/lane ----------------
// v is a dedicated [MTOK][DD] bf16 buffer.
__global__ void scan_pass1(const __bf16* __restrict__ v0,
                           float* __restrict__ csum) {
  int blk = blockIdx.x;
  int bh = blk >> 4, c = blk & 15;
  int b = bh >> 4, h = bh & 15;
  int t = threadIdx.x;
  int rs = t >> 4, dg = t & 15;
  const unsigned short* base = (const unsigned short*)v0 +
      (size_t)(b * SS + c * 128 + rs * 8) * DD + h * HDIM + dg * 8;
  float s[8] = {0.f, 0.f, 0.f, 0.f, 0.f, 0.f, 0.f, 0.f};
#pragma unroll
  for (int i = 0; i < 8; ++i) {
    uint4 u = *(const uint4*)(base + (size_t)i * DD);
    const unsigned short* us = (const unsigned short*)&u;
#pragma unroll
    for (int j = 0; j < 8; ++j) s[j] += bf2f(us[j]);
  }
  __shared__ float red[16 * 128];
#pragma unroll
  for (int j = 0; j < 8; ++j) red[rs * 128 + dg * 8 + j] = s[j];
  __syncthreads();
  for (int st = 8; st >= 1; st >>= 1) {
    if (rs < st) {
#pragma unroll
      for (int j = 0; j < 8; ++j)
        red[rs * 128 + dg * 8 + j] += red[(rs + st) * 128 + dg * 8 + j];
    }
    __syncthreads();
  }
  if (rs == 0) {
#pragma unroll
    for (int j = 0; j < 8; ++j)
      csum[(size_t)blk * 128 + dg * 8 + j] = red[dg * 8 + j];
  }
}

__global__ void scan_pass2(const __bf16* __restrict__ v0,
                           const float* __restrict__ csum,
                           const float* __restrict__ denomA,
                           const float* __restrict__ denomB,
                           const float* __restrict__ diag,
                           unsigned short* __restrict__ ctx) {
  int blk = blockIdx.x;
  int bh = blk >> 4, c = blk & 15;
  int b = bh >> 4, h = bh & 15;
  int t = threadIdx.x;
  int rs = t >> 4, dg = t & 15;
  const unsigned short* vbase = (const unsigned short*)v0 +
      (size_t)(b * SS + c * 128 + rs * 8) * DD + h * HDIM + dg * 8;
  float vrow[8][8];
  float ls[8] = {0.f, 0.f, 0.f, 0.f, 0.f, 0.f, 0.f, 0.f};
#pragma unroll
  for (int i = 0; i < 8; ++i) {
    uint4 u = *(const uint4*)(vbase + (size_t)i * DD);
    const unsigned short* us = (const unsigned short*)&u;
#pragma unroll
    for (int j = 0; j < 8; ++j) {
      vrow[i][j] = bf2f(us[j]);
      ls[j] += vrow[i][j];
    }
  }
  __shared__ float red[16 * 128];
#pragma unroll
  for (int j = 0; j < 8; ++j) red[rs * 128 + dg * 8 + j] = ls[j];
  __syncthreads();

  float pre[8] = {0.f, 0.f, 0.f, 0.f, 0.f, 0.f, 0.f, 0.f};
  for (int cc = 0; cc < c; ++cc) {
    const float* cp = csum + (size_t)(bh * 16 + cc) * 128 + dg * 8;
#pragma unroll
    for (int j = 0; j < 8; ++j) pre[j] += cp[j];
  }
  for (int ss2 = 0; ss2 < rs; ++ss2) {
#pragma unroll
    for (int j = 0; j < 8; ++j) pre[j] += red[ss2 * 128 + dg * 8 + j];
  }

  int row0 = c * 128 + rs * 8;
  unsigned short* obase =
      ctx + (size_t)(b * SS + row0) * DD + h * HDIM + dg * 8;
  const float* dnA = denomA + bh * SS + row0;
  const float* dnB = denomB + bh * SS + row0;
  const float* dgp = diag + bh * SS + row0;
#pragma unroll
  for (int i = 0; i < 8; ++i) {
    float inv = 1.0f / (dnA[i] + dnB[i]);
    float dv = dgp[i];
    unsigned short o[8];
#pragma unroll
    for (int j = 0; j < 8; ++j) {
      float val = (pre[j] + dv * vrow[i][j]) * inv;
      o[j] = f2bf(val);
      pre[j] += vrow[i][j];
    }
    *(uint4*)(obase + (size_t)i * DD) = *(const uint4*)o;
  }
}

extern "C" void kernel_launch(void* const* d_in, const int* in_sizes, int n_in,
                              void* d_out, int out_size, void* d_ws, size_t ws_size,
                              hipStream_t stream) {
  (void)in_sizes; (void)n_in; (void)out_size; (void)ws_size;
  const float* x    = (const float*)d_in[0];
  const float* wq_w = (const float*)d_in[1];
  const float* wq_b = (const float*)d_in[2];
  const float* wk_w = (const float*)d_in[3];
  const float* wk_b = (const float*)d_in[4];
  const float* wv_w = (const float*)d_in[5];
  const float* wv_b = (const float*)d_in[6];
  const float* wo_w = (const float*)d_in[7];
  const float* wo_b = (const float*)d_in[8];

  char* ws = (char*)d_ws;
  size_t off = 0;
  auto alloc = [&](size_t bytes) {
    char* p = ws + off;
    off += (bytes + 255) & ~(size_t)255;
    return p;
  };
  unsigned short* xb   = (unsigned short*)alloc((size_t)MTOK * DD * 2);    // 16 MB
  unsigned char*  x8   = (unsigned char*)alloc((size_t)MTOK * DD);         // 8 MB
  unsigned char*  wqk8 = (unsigned char*)alloc((size_t)2 * DD * DD);       // 8 MB
  unsigned short* wvo  = (unsigned short*)alloc((size_t)2 * DD * DD * 2);  // 16 MB (wv | wo)
  unsigned char*  qk8  = (unsigned char*)alloc((size_t)MTOK * QKN);        // 16 MB
  unsigned short* v    = (unsigned short*)alloc((size_t)MTOK * DD * 2);    // 16 MB
  unsigned short* ctx  = (unsigned short*)alloc((size_t)MTOK * DD * 2);    // 16 MB
  float* biasqk = (float*)alloc((size_t)2 * DD * 4);
  float* denomA = (float*)alloc((size_t)BHH * SS * 4);
  float* denomB = (float*)alloc((size_t)BHH * SS * 4);
  float* diag   = (float*)alloc((size_t)BHH * SS * 4);
  float* csum   = (float*)alloc((size_t)BHH * NCHUNK * 128 * 4);

  // 1) converts
  {
    int n4 = MTOK * DD / 4;
    cvt_x_dual<<<n4 / 256, 256, 0, stream>>>(x, xb, (unsigned int*)x8, n4);
    cvt_wqk8<<<(2 << 20) / 256, 256, 0, stream>>>(wq_w, wk_w, (unsigned int*)wqk8);
    cvt_w2bf<<<(2 << 20) / 256, 256, 0, stream>>>(wv_w, wo_w, wvo);
    concat2<<<(DD + 255) / 256, 256, 0, stream>>>(wq_b, wk_b, biasqk);
  }

  // 2) QK projection, MX-fp8 (counted-vmcnt schedule, natural n-fast grid):
  //    [4096,2048] x [4096,2048]^T -> qk8 [4096][4096] e4m3
  gemm_qk8<<<dim3(QKN / 128, MTOK / 256), 512, 0, stream>>>(
      x8, wqk8, biasqk, qk8, MTOK, QKN, DD);

  // 3) V projection in bf16 -> v [4096][2048]  (8-phase GEMM, BM=256 BN=128)
  gemm_bt8<true><<<(MTOK / 256) * (DD / 128), 512, 0, stream>>>(
      (const __bf16*)xb, (const __bf16*)wvo, wv_b, v, MTOK, DD, DD);

  // 4) denominators + diagonal exps (MX fp8 MFMA, paired i-tiles, 2-way j-split)
  qk_rowsum8<<<dim3(32, BHH), 256, 0, stream>>>(
      qk8,            // q at col 0
      qk8 + DD,       // k at col 2048
      denomA, denomB, diag);

  // 5) V scan -> ctx
  scan_pass1<<<BHH * NCHUNK, 256, 0, stream>>>((const __bf16*)v, csum);
  scan_pass2<<<BHH * NCHUNK, 256, 0, stream>>>((const __bf16*)v, csum,
                                               denomA, denomB, diag, ctx);

  // 6) output projection: [4096,2048] x [2048,2048]^T -> d_out fp32
  gemm_bt8<false><<<(MTOK / 256) * (DD / 128), 512, 0, stream>>>(
      (const __bf16*)ctx, (const __bf16*)(wvo + (size_t)DD * DD), wo_b,
      d_out, MTOK, DD, DD);
}

// Round 7
// 316.289 us; speedup vs baseline: 1.0146x; 1.0119x over previous
//
#include <hip/hip_runtime.h>

// Problem constants
#define BB 2
#define SS 2048
#define DD 2048
#define HH 16
#define HDIM 128
#define MTOK (BB*SS)     // 4096 token rows
#define BHH (BB*HH)      // 32 (b,h) pairs
#define NCHUNK 16        // scan chunks per (b,h): 2048/128
#define QKN (2*DD)       // fp8 qk row stride (q cols 0..2047, k cols 2048..4095)

typedef __attribute__((ext_vector_type(8))) __bf16 bf16x8;
typedef __attribute__((ext_vector_type(4))) float f32x4;
typedef __attribute__((ext_vector_type(8))) int i32x8;
typedef __attribute__((ext_vector_type(4))) int i32x4;

__device__ __forceinline__ unsigned short f2bf(float f) {
  unsigned u = __float_as_uint(f);
  u += 0x7FFFu + ((u >> 16) & 1u);   // RNE
  return (unsigned short)(u >> 16);
}
__device__ __forceinline__ float bf2f(unsigned short s) {
  return __uint_as_float(((unsigned)s) << 16);
}
__device__ __forceinline__ unsigned char f2e4m3(float f) {
  // HW convert, OCP e4m3fn on gfx950, saturating
  int pk = __builtin_amdgcn_cvt_pk_fp8_f32(f, f, 0, false);
  return (unsigned char)(pk & 0xFF);
}

// async global->LDS, 16B per lane; dst must be wave-uniform base (HW adds lane*16)
#define GLOAD_LDS16(src, dst)                                                   \
  __builtin_amdgcn_global_load_lds(                                             \
      (const void __attribute__((address_space(1)))*)(src),                     \
      (void __attribute__((address_space(3)))*)(dst), 16, 0, 0)

__device__ __forceinline__ void barrier_raw() {
  asm volatile("" ::: "memory");
  __builtin_amdgcn_s_barrier();
  asm volatile("" ::: "memory");
}

// ---------------- converts ----------------
// x -> bf16 (for V gemm) and fp8 (for QK gemm) in one pass
__global__ void cvt_x_dual(const float* __restrict__ in,
                           unsigned short* __restrict__ outb,
                           unsigned int* __restrict__ out8, int n4) {
  int i = blockIdx.x * blockDim.x + threadIdx.x;
  if (i < n4) {
    float4 v = ((const float4*)in)[i];
    ushort4 o;
    o.x = f2bf(v.x); o.y = f2bf(v.y); o.z = f2bf(v.z); o.w = f2bf(v.w);
    ((ushort4*)outb)[i] = o;
    int p0 = __builtin_amdgcn_cvt_pk_fp8_f32(v.x, v.y, 0, false);
    int p1 = __builtin_amdgcn_cvt_pk_fp8_f32(v.z, v.w, 0, false);
    out8[i] = (unsigned)(p0 & 0xFFFF) | ((unsigned)(p1 & 0xFFFF) << 16);
  }
}

// fused weight converts: wq,wk -> fp8 [2*DD][DD]; wv,wo -> bf16 (wv|wo); bias concat
// region-branched grid: [0,8192) fp8, [8192,16384) bf16, [16384,16400) bias
__global__ void cvt_w_all(const float* __restrict__ wq, const float* __restrict__ wk,
                          const float* __restrict__ wv, const float* __restrict__ wo,
                          const float* __restrict__ wqb, const float* __restrict__ wkb,
                          unsigned int* __restrict__ out8,
                          unsigned short* __restrict__ outb,
                          float* __restrict__ biasqk) {
  int blk = blockIdx.x;
  int tid = threadIdx.x;
  if (blk < 8192) {
    int i = blk * 256 + tid;              // < 2<<20
    int sel = i >> 20, r = i & 0xFFFFF;   // DD*DD/4 == 1<<20
    const float* src = sel == 0 ? wq : wk;
    float4 v = ((const float4*)src)[r];
    int p0 = __builtin_amdgcn_cvt_pk_fp8_f32(v.x, v.y, 0, false);
    int p1 = __builtin_amdgcn_cvt_pk_fp8_f32(v.z, v.w, 0, false);
    out8[i] = (unsigned)(p0 & 0xFFFF) | ((unsigned)(p1 & 0xFFFF) << 16);
  } else if (blk < 16384) {
    int i = (blk - 8192) * 256 + tid;
    int sel = i >> 20, r = i & 0xFFFFF;
    const float* src = sel == 0 ? wv : wo;
    float4 v = ((const float4*)src)[r];
    ushort4 o;
    o.x = f2bf(v.x); o.y = f2bf(v.y); o.z = f2bf(v.z); o.w = f2bf(v.w);
    ((ushort4*)outb)[i] = o;
  } else {
    int i = (blk - 16384) * 256 + tid;    // < 4096 = 2*DD
    biasqk[i] = (i < DD) ? wqb[i] : wkb[i - DD];
  }
}

// ---------------- bf16 GEMM v8: C[M][N] = A[M][K] @ W[N][K]^T + bias[N] ----------
// 8-phase-class schedule (T1+T2+T3+T4+T5):
//   BM=256, BN=128, BK=64, 512 threads = 8 waves (4M x 2N), 64x64 out per wave.
//   Counted vmcnt, chunk-XOR swizzle via pre-swizzled global source, XCD remap
//   (m-contiguous per XCD). Measured: 57.3 -> ~41 us vs the 2-barrier 128^2 form.
template <bool OUT_BF16>
__global__ __launch_bounds__(512, 1) void gemm_bt8(
    const __bf16* __restrict__ A, const __bf16* __restrict__ W,
    const float* __restrict__ bias, void* __restrict__ Cout,
    int M, int N, int K) {
  // [buf][A: 256 rows x 128 B | B: 128 rows x 128 B] = 2 x 48 KB
  __shared__ unsigned char lds[2][49152];
  const int t = threadIdx.x;
  const int lane = t & 63, wave = t >> 6;      // wave 0..7
  const int quad = lane >> 4, l16 = lane & 15;
  const int bid = blockIdx.x;                  // 256 blocks
  const int swz = (bid & 7) * 32 + (bid >> 3); // XCD-contiguous remap (256%8==0)
  const int m0 = (swz >> 4) * 256;
  const int n0 = (swz & 15) * 128;
  const int wm = (wave >> 1) * 64;             // 0,64,128,192
  const int wn = (wave & 1) * 64;              // 0,64

  // stage sources (pre-swizzled): LDS phys chunk p of row r holds global chunk
  // p ^ (r&7).  A = rounds 0..3 (rows 0..255), B = rounds 0..1 (rows 0..127).
  const __bf16* sA[4];
#pragma unroll
  for (int c = 0; c < 4; ++c) {
    int L = c * 512 + t;
    int row = L >> 3, p = L & 7;
    sA[c] = A + (size_t)(m0 + row) * K + ((p ^ (row & 7)) * 8);
  }
  const __bf16* sB[2];
#pragma unroll
  for (int c = 0; c < 2; ++c) {
    int L = c * 512 + t;
    int row = L >> 3, p = L & 7;
    sB[c] = W + (size_t)(n0 + row) * K + ((p ^ (row & 7)) * 8);
  }
  // read-side phys chunk per (kh, quad): (kh*4 + quad) ^ (l16&7)
  const int phk0 = (quad ^ (l16 & 7)) * 16;
  const int phk1 = ((4 + quad) ^ (l16 & 7)) * 16;

  f32x4 acc[4][4] = {};

  const int NT = K >> 6;  // 64-wide K-tiles

  // prologue: stage tile 0 into buf 0 (6 loads/thread)
#pragma unroll
  for (int c = 0; c < 4; ++c)
    GLOAD_LDS16(sA[c], &lds[0][c * 8192 + wave * 1024]);
#pragma unroll
  for (int c = 0; c < 2; ++c)
    GLOAD_LDS16(sB[c], &lds[0][32768 + c * 8192 + wave * 1024]);

  for (int tt = 0; tt < NT; ++tt) {
    const int cur = tt & 1;
    const bool pf = (tt + 1 < NT);
    const int k1 = (tt + 1) << 6;

    // ---- phase 0 (k-half 0) ----
    if (pf) {
#pragma unroll
      for (int c = 0; c < 4; ++c)
        GLOAD_LDS16(sA[c] + k1, &lds[cur ^ 1][c * 8192 + wave * 1024]);
      asm volatile("s_waitcnt vmcnt(4)" ::: "memory");  // tile-t loads landed
    } else {
      asm volatile("s_waitcnt vmcnt(0)" ::: "memory");
    }
    barrier_raw();
    {
      bf16x8 af[4], bfv[4];
#pragma unroll
      for (int mt = 0; mt < 4; ++mt)
        af[mt] = *(const bf16x8*)&lds[cur][(wm + mt * 16 + l16) * 128 + phk0];
#pragma unroll
      for (int nt = 0; nt < 4; ++nt)
        bfv[nt] = *(const bf16x8*)&lds[cur][32768 + (wn + nt * 16 + l16) * 128 + phk0];
      __builtin_amdgcn_s_setprio(1);
#pragma unroll
      for (int mt = 0; mt < 4; ++mt)
#pragma unroll
        for (int nt = 0; nt < 4; ++nt)
          acc[mt][nt] = __builtin_amdgcn_mfma_f32_16x16x32_bf16(
              af[mt], bfv[nt], acc[mt][nt], 0, 0, 0);
      __builtin_amdgcn_s_setprio(0);
    }

    // ---- phase 1 (k-half 1) ----
    if (pf) {
#pragma unroll
      for (int c = 0; c < 2; ++c)
        GLOAD_LDS16(sB[c] + k1, &lds[cur ^ 1][32768 + c * 8192 + wave * 1024]);
    }
    barrier_raw();
    {
      bf16x8 af[4], bfv[4];
#pragma unroll
      for (int mt = 0; mt < 4; ++mt)
        af[mt] = *(const bf16x8*)&lds[cur][(wm + mt * 16 + l16) * 128 + phk1];
#pragma unroll
      for (int nt = 0; nt < 4; ++nt)
        bfv[nt] = *(const bf16x8*)&lds[cur][32768 + (wn + nt * 16 + l16) * 128 + phk1];
      __builtin_amdgcn_s_setprio(1);
#pragma unroll
      for (int mt = 0; mt < 4; ++mt)
#pragma unroll
        for (int nt = 0; nt < 4; ++nt)
          acc[mt][nt] = __builtin_amdgcn_mfma_f32_16x16x32_bf16(
              af[mt], bfv[nt], acc[mt][nt], 0, 0, 0);
      __builtin_amdgcn_s_setprio(0);
    }
    barrier_raw();  // all waves done reading buf[cur] before tt+1 overwrites it
  }

  // epilogue: C/D layout col=lane&15, row=quad*4+reg  [m89/m91 verified]
#pragma unroll
  for (int mt = 0; mt < 4; ++mt) {
#pragma unroll
    for (int nt = 0; nt < 4; ++nt) {
      int col = n0 + wn + nt * 16 + l16;
      float bv = bias[col];
#pragma unroll
      for (int r = 0; r < 4; ++r) {
        int row = m0 + wm + mt * 16 + quad * 4 + r;
        float v = acc[mt][nt][r] + bv;
        if constexpr (OUT_BF16)
          ((unsigned short*)Cout)[(size_t)row * N + col] = f2bf(v);
        else
          ((float*)Cout)[(size_t)row * N + col] = v;
      }
    }
  }
}

// ---------------- fp8 MX GEMM v10: C8[M][N] = e4m3( A8 @ W8^T + bias ) -----------
// Round-6 post-mortem: at BM=256 (96 KB LDS, 1 block/CU) the counted-vmcnt
// schedule LOST to the old 2-blocks/CU 2-barrier form (49.4 vs 46.8) and fixing
// L2 locality (FETCH 70->41 MB) changed nothing -> occupancy, not locality or
// schedule, limits fp8. v10 combines both proven ingredients:
//   BM=128, BN=128, BK=128, 256 threads (4 waves 2x2), dbuf 64 KB LDS
//   -> 2 blocks/CU, PLUS counted vmcnt + chunk-XOR swizzle + setprio.
//   Per tile: phase 0 {issue 4xA(t+1), vmcnt(4), barrier, A-frags + B nt0,1},
//             phase 1 {issue 4xB(t+1), barrier, B nt2,3}, trailing barrier.
//   vmcnt: steady-state outstanding = 8 (tile t) + 4 (new A) -> vmcnt(4)
//   retires exactly tile t's 8; never drains to 0 in the main loop.
//   Natural n-fastest grid (32,32): per-XCD B set = 4 panels = 1 MB, L2-resident.
__global__ __launch_bounds__(256, 2) void gemm_qk8(
    const unsigned char* __restrict__ A8, const unsigned char* __restrict__ W8,
    const float* __restrict__ bias, unsigned char* __restrict__ Cout,
    int M, int N, int K) {
  // [buf][A: 128 rows x 128 B | B: 128 rows x 128 B] = 2 x 32 KB
  __shared__ unsigned char lds[2][32768];
  const int t = threadIdx.x;
  const int lane = t & 63, wave = t >> 6;      // 0..3
  const int quad = lane >> 4, l16 = lane & 15;
  const int m0 = blockIdx.y * 128;
  const int n0 = blockIdx.x * 128;             // fastest -> XCD ~ n%8
  const int wm = (wave & 1) * 64, wn = (wave >> 1) * 64;

  // stage sources (pre-swizzled): LDS phys chunk p of row r holds global chunk
  // p ^ (r&7). 1024 chunks per matrix, 4 rounds of 256 threads each.
  const unsigned char* sA[4];
  const unsigned char* sB[4];
#pragma unroll
  for (int c = 0; c < 4; ++c) {
    int L = c * 256 + t;
    int row = L >> 3, p = L & 7;
    int sc = (p ^ (row & 7)) * 16;
    sA[c] = A8 + (size_t)(m0 + row) * K + sc;
    sB[c] = W8 + (size_t)(n0 + row) * K + sc;
  }
  const int p0 = (2 * quad) ^ (l16 & 7);   // phys chunk of logical chunk 2*quad

  f32x4 acc[4][4] = {};

  const int NT = K >> 7;  // 128-wide K-tiles (16)

  // prologue: stage tile 0 into buf 0 (8 loads/thread)
#pragma unroll
  for (int c = 0; c < 4; ++c)
    GLOAD_LDS16(sA[c], &lds[0][(c * 256 + wave * 64) * 16]);
#pragma unroll
  for (int c = 0; c < 4; ++c)
    GLOAD_LDS16(sB[c], &lds[0][16384 + (c * 256 + wave * 64) * 16]);

  for (int tt = 0; tt < NT; ++tt) {
    const int cur = tt & 1;
    const bool pf = (tt + 1 < NT);
    const int k1 = (tt + 1) << 7;

    // ---- phase 0: issue A(t+1), retire tile t's loads, compute nt 0,1 ----
    if (pf) {
#pragma unroll
      for (int c = 0; c < 4; ++c)
        GLOAD_LDS16(sA[c] + k1, &lds[cur ^ 1][(c * 256 + wave * 64) * 16]);
      asm volatile("s_waitcnt vmcnt(4)" ::: "memory");  // tile-t's 8 landed
    } else {
      asm volatile("s_waitcnt vmcnt(0)" ::: "memory");
    }
    barrier_raw();
    i32x8 af[4];
    {
#pragma unroll
      for (int mt = 0; mt < 4; ++mt) {
        int ra = (wm + mt * 16 + l16) * 128 + p0 * 16;
        ((i32x4*)&af[mt])[0] = *(const i32x4*)&lds[cur][ra];
        ((i32x4*)&af[mt])[1] = *(const i32x4*)&lds[cur][ra ^ 16];
      }
      i32x8 bv[2];
#pragma unroll
      for (int nt = 0; nt < 2; ++nt) {
        int rb = 16384 + (wn + nt * 16 + l16) * 128 + p0 * 16;
        ((i32x4*)&bv[nt])[0] = *(const i32x4*)&lds[cur][rb];
        ((i32x4*)&bv[nt])[1] = *(const i32x4*)&lds[cur][rb ^ 16];
      }
      __builtin_amdgcn_s_setprio(1);
#pragma unroll
      for (int mt = 0; mt < 4; ++mt)
#pragma unroll
        for (int nt = 0; nt < 2; ++nt)
          acc[mt][nt] = __builtin_amdgcn_mfma_scale_f32_16x16x128_f8f6f4(
              af[mt], bv[nt], acc[mt][nt], 0, 0, 0, 127, 0, 127);
      __builtin_amdgcn_s_setprio(0);
    }

    // ---- phase 1: issue B(t+1), compute nt 2,3 ----
    if (pf) {
#pragma unroll
      for (int c = 0; c < 4; ++c)
        GLOAD_LDS16(sB[c] + k1, &lds[cur ^ 1][16384 + (c * 256 + wave * 64) * 16]);
    }
    barrier_raw();
    {
      i32x8 bv[2];
#pragma unroll
      for (int nt = 0; nt < 2; ++nt) {
        int rb = 16384 + (wn + (nt + 2) * 16 + l16) * 128 + p0 * 16;
        ((i32x4*)&bv[nt])[0] = *(const i32x4*)&lds[cur][rb];
        ((i32x4*)&bv[nt])[1] = *(const i32x4*)&lds[cur][rb ^ 16];
      }
      __builtin_amdgcn_s_setprio(1);
#pragma unroll
      for (int mt = 0; mt < 4; ++mt)
#pragma unroll
        for (int nt = 0; nt < 2; ++nt)
          acc[mt][nt + 2] = __builtin_amdgcn_mfma_scale_f32_16x16x128_f8f6f4(
              af[mt], bv[nt], acc[mt][nt + 2], 0, 0, 0, 127, 0, 127);
      __builtin_amdgcn_s_setprio(0);
    }
    barrier_raw();  // all waves done reading buf[cur] before tt+1 overwrites it
  }

  // epilogue: C/D layout shape-determined, same as 16x16x32 [m121-m128]
#pragma unroll
  for (int mt = 0; mt < 4; ++mt) {
#pragma unroll
    for (int nt = 0; nt < 4; ++nt) {
      int col = n0 + wn + nt * 16 + l16;
      float bv = bias[col];
#pragma unroll
      for (int r = 0; r < 4; ++r) {
        int row = m0 + wm + mt * 16 + quad * 4 + r;
        Cout[(size_t)row * N + col] = f2e4m3(acc[mt][nt][r] + bv);
      }
    }
  }
}

// ---------------- QK^T upper-triangle exp row-sums + diagonal (MX fp8) ----------------
//  - one mfma_scale 16x16x128 per 16x16 score tile (K=128 = whole head-dim)
//  - waves split by COLUMN (each wave: 32 cols x all 64 rows)
//  - chunk-XOR swizzle staged via pre-swizzled global source
//  - diagonal/masked logic peeled into the first j-tile only
//  - 2-phase double-buffered staging; 2-way j-split (grid.x = 32)
__global__ __launch_bounds__(256, 4) void qk_rowsum8(
    const unsigned char* __restrict__ q8, const unsigned char* __restrict__ k8,
    float* __restrict__ denomA, float* __restrict__ denomB,
    float* __restrict__ diag) {
  __shared__ unsigned char lK[2][128 * 128];  // 32 KB double-buffered
  __shared__ float redS[4][64];
  __shared__ float redD[4][64];
  const int t = threadIdx.x;
  const int lane = t & 63, wave = t >> 6;
  const int quad = lane >> 4, l16 = lane & 15;
  const int bh = blockIdx.y;
  const int b = bh >> 4, h = bh & 15;
  const int pair = blockIdx.x >> 1;       // 0..15 (work-balanced i-tile pair)
  const int half = blockIdx.x & 1;        // j-split: tiles with k%2==half
  const float C = 0.03187935771f;         // (1/sqrt(2048)) * log2(e)
  const f32x4 fz = {0.f, 0.f, 0.f, 0.f};

  // staging source offsets (swizzled): LDS chunk L holds global chunk (L&7)^(row&7)
  int soff[4];
#pragma unroll
  for (int c = 0; c < 4; ++c) {
    int L = c * 256 + t;
    int row = L >> 3, p = L & 7;
    soff[c] = row * QKN + ((p ^ (row & 7)) * 16);
  }
  // LDS read byte offsets: B-row r = wave*32 + nt*16 + l16, phys chunk (2q)^(l16&7)
  const int p0 = (2 * quad) ^ (l16 & 7);
  int bo[2];
#pragma unroll
  for (int nt = 0; nt < 2; ++nt)
    bo[nt] = (wave * 32 + nt * 16 + l16) * 128 + p0 * 16;

  const unsigned char* kbase = k8 + (size_t)(b * SS) * QKN + h * HDIM;

  for (int sub = 0; sub < 2; ++sub) {
    const int tile = (sub == 0) ? pair : 31 - pair;
    const int i0 = tile * 64;
    const int jbase = i0 & ~127;
    const int ntile = (SS - jbase) >> 7;

    // A fragments: Q rows i0 + mt*16 + l16, k-bytes quad*32 (held in regs)
    i32x8 af[4];
    {
      const unsigned char* qbase =
          q8 + (size_t)(b * SS + i0 + l16) * QKN + h * HDIM + quad * 32;
#pragma unroll
      for (int mt = 0; mt < 4; ++mt)
        af[mt] = *(const i32x8*)(qbase + (size_t)(mt * 16) * QKN);
    }

    float rowacc[4][4] = {};

    int kidx = half;
    if (kidx < ntile) {
      {  // prologue: stage first tile into buf 0
        const unsigned char* src = kbase + (size_t)(jbase + kidx * 128) * QKN;
#pragma unroll
        for (int c = 0; c < 4; ++c)
          GLOAD_LDS16(src + soff[c], &lK[0][(c * 256 + wave * 64) * 16]);
      }
      asm volatile("s_waitcnt vmcnt(0)" ::: "memory");
      __syncthreads();
      int cur = 0;
      for (; kidx < ntile; kidx += 2, cur ^= 1) {
        if (kidx + 2 < ntile) {  // issue next-tile stage before compute
          const unsigned char* src =
              kbase + (size_t)(jbase + (kidx + 2) * 128) * QKN;
#pragma unroll
          for (int c = 0; c < 4; ++c)
            GLOAD_LDS16(src + soff[c], &lK[cur ^ 1][(c * 256 + wave * 64) * 16]);
        }
        const unsigned char* lkc = lK[cur];
        const int j0 = jbase + kidx * 128;
        if (kidx == 0) {
          // diagonal/masked tile (always half 0's first tile)
          float dloc[4][4] = {};
#pragma unroll
          for (int nt = 0; nt < 2; ++nt) {
            i32x8 bf;
            ((i32x4*)&bf)[0] = *(const i32x4*)(lkc + bo[nt]);
            ((i32x4*)&bf)[1] = *(const i32x4*)(lkc + (bo[nt] ^ 16));
            f32x4 acc[4];
#pragma unroll
            for (int mt = 0; mt < 4; ++mt)
              acc[mt] = __builtin_amdgcn_mfma_scale_f32_16x16x128_f8f6f4(
                  af[mt], bf, fz, 0, 0, 0, 127, 0, 127);
            const int colg = j0 + wave * 32 + nt * 16 + l16;
#pragma unroll
            for (int mt = 0; mt < 4; ++mt)
#pragma unroll
              for (int r = 0; r < 4; ++r) {
                int rg = i0 + mt * 16 + quad * 4 + r;
                float e = (colg >= rg)
                              ? __builtin_amdgcn_exp2f(acc[mt][r] * C) : 0.f;
                rowacc[mt][r] += e;
                if (colg == rg) dloc[mt][r] = e;
              }
          }
          // reduce + stash diag immediately (frees dloc registers)
#pragma unroll
          for (int mt = 0; mt < 4; ++mt)
#pragma unroll
            for (int r = 0; r < 4; ++r) {
              float d = dloc[mt][r];
#pragma unroll
              for (int off = 1; off < 16; off <<= 1) d += __shfl_xor(d, off, 64);
              if (l16 == 0) redD[wave][mt * 16 + quad * 4 + r] = d;
            }
        } else {
          // unmasked: all cols > all rows
#pragma unroll
          for (int nt = 0; nt < 2; ++nt) {
            i32x8 bf;
            ((i32x4*)&bf)[0] = *(const i32x4*)(lkc + bo[nt]);
            ((i32x4*)&bf)[1] = *(const i32x4*)(lkc + (bo[nt] ^ 16));
            f32x4 acc[4];
#pragma unroll
            for (int mt = 0; mt < 4; ++mt)
              acc[mt] = __builtin_amdgcn_mfma_scale_f32_16x16x128_f8f6f4(
                  af[mt], bf, fz, 0, 0, 0, 127, 0, 127);
#pragma unroll
            for (int mt = 0; mt < 4; ++mt)
#pragma unroll
              for (int r = 0; r < 4; ++r)
                rowacc[mt][r] += __builtin_amdgcn_exp2f(acc[mt][r] * C);
          }
        }
        asm volatile("s_waitcnt vmcnt(0)" ::: "memory");
        __syncthreads();
      }
    }

    // cross-wave reduction (redS/redD reused across subs -> barrier first)
    __syncthreads();
#pragma unroll
    for (int mt = 0; mt < 4; ++mt)
#pragma unroll
      for (int r = 0; r < 4; ++r) {
        float s = rowacc[mt][r];
#pragma unroll
        for (int off = 1; off < 16; off <<= 1) s += __shfl_xor(s, off, 64);
        if (l16 == 0) redS[wave][mt * 16 + quad * 4 + r] = s;
      }
    __syncthreads();
    if (t < 64) {
      const int rg = i0 + t;
      float s = redS[0][t] + redS[1][t] + redS[2][t] + redS[3][t];
      if (half == 0) {
        denomA[bh * SS + rg] = (float)rg + s;
        diag[bh * SS + rg] = redD[0][t] + redD[1][t] + redD[2][t] + redD[3][t];
      } else {
        denomB[bh * SS + rg] = s;
      }
    }
  }
}

// ---------------- V prefix-scan, two-pass, 16B/lane ----------------
// v is a dedicated [MTOK][DD] bf16 buffer.
__global__ void scan_pass1(const __bf16* __restrict__ v0,
                           float* __restrict__ csum) {
  int blk = blockIdx.x;
  int bh = blk >> 4, c = blk & 15;
  int b = bh >> 4, h = bh & 15;
  int t = threadIdx.x;
  int rs = t >> 4, dg = t & 15;
  const unsigned short* base = (const unsigned short*)v0 +
      (size_t)(b * SS + c * 128 + rs * 8) * DD + h * HDIM + dg * 8;
  float s[8] = {0.f, 0.f, 0.f, 0.f, 0.f, 0.f, 0.f, 0.f};
#pragma unroll
  for (int i = 0; i < 8; ++i) {
    uint4 u = *(const uint4*)(base + (size_t)i * DD);
    const unsigned short* us = (const unsigned short*)&u;
#pragma unroll
    for (int j = 0; j < 8; ++j) s[j] += bf2f(us[j]);
  }
  __shared__ float red[16 * 128];
#pragma unroll
  for (int j = 0; j < 8; ++j) red[rs * 128 + dg * 8 + j] = s[j];
  __syncthreads();
  for (int st = 8; st >= 1; st >>= 1) {
    if (rs < st) {
#pragma unroll
      for (int j = 0; j < 8; ++j)
        red[rs * 128 + dg * 8 + j] += red[(rs + st) * 128 + dg * 8 + j];
    }
    __syncthreads();
  }
  if (rs == 0) {
#pragma unroll
    for (int j = 0; j < 8; ++j)
      csum[(size_t)blk * 128 + dg * 8 + j] = red[dg * 8 + j];
  }
}

__global__ void scan_pass2(const __bf16* __restrict__ v0,
                           const float* __restrict__ csum,
                           const float* __restrict__ denomA,
                           const float* __restrict__ denomB,
                           const float* __restrict__ diag,
                           unsigned short* __restrict__ ctx) {
  int blk = blockIdx.x;
  int bh = blk >> 4, c = blk & 15;
  int b = bh >> 4, h = bh & 15;
  int t = threadIdx.x;
  int rs = t >> 4, dg = t & 15;
  const unsigned short* vbase = (const unsigned short*)v0 +
      (size_t)(b * SS + c * 128 + rs * 8) * DD + h * HDIM + dg * 8;
  float vrow[8][8];
  float ls[8] = {0.f, 0.f, 0.f, 0.f, 0.f, 0.f, 0.f, 0.f};
#pragma unroll
  for (int i = 0; i < 8; ++i) {
    uint4 u = *(const uint4*)(vbase + (size_t)i * DD);
    const unsigned short* us = (const unsigned short*)&u;
#pragma unroll
    for (int j = 0; j < 8; ++j) {
      vrow[i][j] = bf2f(us[j]);
      ls[j] += vrow[i][j];
    }
  }
  __shared__ float red[16 * 128];
#pragma unroll
  for (int j = 0; j < 8; ++j) red[rs * 128 + dg * 8 + j] = ls[j];
  __syncthreads();

  float pre[8] = {0.f, 0.f, 0.f, 0.f, 0.f, 0.f, 0.f, 0.f};
  for (int cc = 0; cc < c; ++cc) {
    const float* cp = csum + (size_t)(bh * 16 + cc) * 128 + dg * 8;
#pragma unroll
    for (int j = 0; j < 8; ++j) pre[j] += cp[j];
  }
  for (int ss2 = 0; ss2 < rs; ++ss2) {
#pragma unroll
    for (int j = 0; j < 8; ++j) pre[j] += red[ss2 * 128 + dg * 8 + j];
  }

  int row0 = c * 128 + rs * 8;
  unsigned short* obase =
      ctx + (size_t)(b * SS + row0) * DD + h * HDIM + dg * 8;
  const float* dnA = denomA + bh * SS + row0;
  const float* dnB = denomB + bh * SS + row0;
  const float* dgp = diag + bh * SS + row0;
#pragma unroll
  for (int i = 0; i < 8; ++i) {
    float inv = 1.0f / (dnA[i] + dnB[i]);
    float dv = dgp[i];
    unsigned short o[8];
#pragma unroll
    for (int j = 0; j < 8; ++j) {
      float val = (pre[j] + dv * vrow[i][j]) * inv;
      o[j] = f2bf(val);
      pre[j] += vrow[i][j];
    }
    *(uint4*)(obase + (size_t)i * DD) = *(const uint4*)o;
  }
}

extern "C" void kernel_launch(void* const* d_in, const int* in_sizes, int n_in,
                              void* d_out, int out_size, void* d_ws, size_t ws_size,
                              hipStream_t stream) {
  (void)in_sizes; (void)n_in; (void)out_size; (void)ws_size;
  const float* x    = (const float*)d_in[0];
  const float* wq_w = (const float*)d_in[1];
  const float* wq_b = (const float*)d_in[2];
  const float* wk_w = (const float*)d_in[3];
  const float* wk_b = (const float*)d_in[4];
  const float* wv_w = (const float*)d_in[5];
  const float* wv_b = (const float*)d_in[6];
  const float* wo_w = (const float*)d_in[7];
  const float* wo_b = (const float*)d_in[8];

  char* ws = (char*)d_ws;
  size_t off = 0;
  auto alloc = [&](size_t bytes) {
    char* p = ws + off;
    off += (bytes + 255) & ~(size_t)255;
    return p;
  };
  unsigned short* xb   = (unsigned short*)alloc((size_t)MTOK * DD * 2);    // 16 MB
  unsigned char*  x8   = (unsigned char*)alloc((size_t)MTOK * DD);         // 8 MB
  unsigned char*  wqk8 = (unsigned char*)alloc((size_t)2 * DD * DD);       // 8 MB
  unsigned short* wvo  = (unsigned short*)alloc((size_t)2 * DD * DD * 2);  // 16 MB (wv | wo)
  unsigned char*  qk8  = (unsigned char*)alloc((size_t)MTOK * QKN);        // 16 MB
  unsigned short* v    = (unsigned short*)alloc((size_t)MTOK * DD * 2);    // 16 MB
  unsigned short* ctx  = (unsigned short*)alloc((size_t)MTOK * DD * 2);    // 16 MB
  float* biasqk = (float*)alloc((size_t)2 * DD * 4);
  float* denomA = (float*)alloc((size_t)BHH * SS * 4);
  float* denomB = (float*)alloc((size_t)BHH * SS * 4);
  float* diag   = (float*)alloc((size_t)BHH * SS * 4);
  float* csum   = (float*)alloc((size_t)BHH * NCHUNK * 128 * 4);

  // 1) converts (x-convert + fused weight/bias converts)
  {
    int n4 = MTOK * DD / 4;
    cvt_x_dual<<<n4 / 256, 256, 0, stream>>>(x, xb, (unsigned int*)x8, n4);
    cvt_w_all<<<16400, 256, 0, stream>>>(wq_w, wk_w, wv_w, wo_w, wq_b, wk_b,
                                         (unsigned int*)wqk8, wvo, biasqk);
  }

  // 2) QK projection, MX-fp8 (2 blocks/CU + counted vmcnt, n-fast grid):
  //    [4096,2048] x [4096,2048]^T -> qk8 [4096][4096] e4m3
  gemm_qk8<<<dim3(QKN / 128, MTOK / 128), 256, 0, stream>>>(
      x8, wqk8, biasqk, qk8, MTOK, QKN, DD);

  // 3) V projection in bf16 -> v [4096][2048]  (8-phase GEMM, BM=256 BN=128)
  gemm_bt8<true><<<(MTOK / 256) * (DD / 128), 512, 0, stream>>>(
      (const __bf16*)xb, (const __bf16*)wvo, wv_b, v, MTOK, DD, DD);

  // 4) denominators + diagonal exps (MX fp8 MFMA, paired i-tiles, 2-way j-split)
  qk_rowsum8<<<dim3(32, BHH), 256, 0, stream>>>(
      qk8,            // q at col 0
      qk8 + DD,       // k at col 2048
      denomA, denomB, diag);

  // 5) V scan -> ctx
  scan_pass1<<<BHH * NCHUNK, 256, 0, stream>>>((const __bf16*)v, csum);
  scan_pass2<<<BHH * NCHUNK, 256, 0, stream>>>((const __bf16*)v, csum,
                                               denomA, denomB, diag, ctx);

  // 6) output projection: [4096,2048] x [2048,2048]^T -> d_out fp32
  gemm_bt8<false><<<(MTOK / 256) * (DD / 128), 512, 0, stream>>>(
      (const __bf16*)ctx, (const __bf16*)(wvo + (size_t)DD * DD), wo_b,
      d_out, MTOK, DD, DD);
}

// Round 9
// 314.552 us; speedup vs baseline: 1.0202x; 1.0055x over previous
//
#include <hip/hip_runtime.h>

// Problem constants
#define BB 2
#define SS 2048
#define DD 2048
#define HH 16
#define HDIM 128
#define MTOK (BB*SS)     // 4096 token rows
#define BHH (BB*HH)      // 32 (b,h) pairs
#define NCHUNK 16        // scan chunks per (b,h): 2048/128
#define QKN (2*DD)       // fp8 qk row stride (q cols 0..2047, k cols 2048..4095)

typedef __attribute__((ext_vector_type(8))) __bf16 bf16x8;
typedef __attribute__((ext_vector_type(4))) float f32x4;
typedef __attribute__((ext_vector_type(8))) int i32x8;
typedef __attribute__((ext_vector_type(4))) int i32x4;

__device__ __forceinline__ unsigned short f2bf(float f) {
  unsigned u = __float_as_uint(f);
  u += 0x7FFFu + ((u >> 16) & 1u);   // RNE
  return (unsigned short)(u >> 16);
}
__device__ __forceinline__ float bf2f(unsigned short s) {
  return __uint_as_float(((unsigned)s) << 16);
}
__device__ __forceinline__ unsigned char f2e4m3(float f) {
  // HW convert, OCP e4m3fn on gfx950, saturating
  int pk = __builtin_amdgcn_cvt_pk_fp8_f32(f, f, 0, false);
  return (unsigned char)(pk & 0xFF);
}

// async global->LDS, 16B per lane; dst must be wave-uniform base (HW adds lane*16)
#define GLOAD_LDS16(src, dst)                                                   \
  __builtin_amdgcn_global_load_lds(                                             \
      (const void __attribute__((address_space(1)))*)(src),                     \
      (void __attribute__((address_space(3)))*)(dst), 16, 0, 0)

__device__ __forceinline__ void barrier_raw() {
  asm volatile("" ::: "memory");
  __builtin_amdgcn_s_barrier();
  asm volatile("" ::: "memory");
}

// ---------------- converts ----------------
// x -> bf16 (for V gemm) and fp8 (for QK gemm) in one pass
__global__ void cvt_x_dual(const float* __restrict__ in,
                           unsigned short* __restrict__ outb,
                           unsigned int* __restrict__ out8, int n4) {
  int i = blockIdx.x * blockDim.x + threadIdx.x;
  if (i < n4) {
    float4 v = ((const float4*)in)[i];
    ushort4 o;
    o.x = f2bf(v.x); o.y = f2bf(v.y); o.z = f2bf(v.z); o.w = f2bf(v.w);
    ((ushort4*)outb)[i] = o;
    int p0 = __builtin_amdgcn_cvt_pk_fp8_f32(v.x, v.y, 0, false);
    int p1 = __builtin_amdgcn_cvt_pk_fp8_f32(v.z, v.w, 0, false);
    out8[i] = (unsigned)(p0 & 0xFFFF) | ((unsigned)(p1 & 0xFFFF) << 16);
  }
}

// fused weight converts: wq,wk -> fp8 [2*DD][DD]; wv,wo -> bf16 (wv|wo); bias concat
// region-branched grid: [0,8192) fp8, [8192,16384) bf16, [16384,16400) bias
__global__ void cvt_w_all(const float* __restrict__ wq, const float* __restrict__ wk,
                          const float* __restrict__ wv, const float* __restrict__ wo,
                          const float* __restrict__ wqb, const float* __restrict__ wkb,
                          unsigned int* __restrict__ out8,
                          unsigned short* __restrict__ outb,
                          float* __restrict__ biasqk) {
  int blk = blockIdx.x;
  int tid = threadIdx.x;
  if (blk < 8192) {
    int i = blk * 256 + tid;              // < 2<<20
    int sel = i >> 20, r = i & 0xFFFFF;   // DD*DD/4 == 1<<20
    const float* src = sel == 0 ? wq : wk;
    float4 v = ((const float4*)src)[r];
    int p0 = __builtin_amdgcn_cvt_pk_fp8_f32(v.x, v.y, 0, false);
    int p1 = __builtin_amdgcn_cvt_pk_fp8_f32(v.z, v.w, 0, false);
    out8[i] = (unsigned)(p0 & 0xFFFF) | ((unsigned)(p1 & 0xFFFF) << 16);
  } else if (blk < 16384) {
    int i = (blk - 8192) * 256 + tid;
    int sel = i >> 20, r = i & 0xFFFFF;
    const float* src = sel == 0 ? wv : wo;
    float4 v = ((const float4*)src)[r];
    ushort4 o;
    o.x = f2bf(v.x); o.y = f2bf(v.y); o.z = f2bf(v.z); o.w = f2bf(v.w);
    ((ushort4*)outb)[i] = o;
  } else {
    int i = (blk - 16384) * 256 + tid;    // < 4096 = 2*DD
    biasqk[i] = (i < DD) ? wqb[i] : wkb[i - DD];
  }
}

// ---------------- bf16 GEMM v9: C[M][N] = A[M][K] @ W[N][K]^T + bias[N] ----------
// 4 fine phases per K-tile (m201-shaped interleave; round-7 post-mortem: the
// coarse 2-phase lockstep left MfmaUtil at 29.5% with no pipe saturated):
//   BM=256, BN=128, BK=64, 512 threads = 8 waves (4M x 2N), 64x64 out per wave.
//   P0 {stage 2xA(t+1); vmcnt(2); barrier; read af.kh0 + bf.kh0[0,1]; 8 MFMA}
//   P1 {read bf.kh0[2,3] PRE-barrier; stage 2xA; barrier; 8 MFMA}
//   P2 {read af.kh1 + bf.kh1[0,1]; stage 1xB; barrier; 8 MFMA}
//   P3 {read bf.kh1[2,3]; stage 1xB; barrier; 8 MFMA; trailing barrier}
//   Pre-barrier ds_reads overlap other waves' MFMA of the previous phase ->
//   LDS and MFMA pipes co-run instead of alternating.
//   vmcnt: 6 loads/tile issued 2+2+1+1; at P0 outstanding = 6 old + 2 new
//   -> vmcnt(2) retires exactly tile t's. Trailing barrier fences t+1's stage
//   writes into the buffer tile t read. Per-element K order kh0->kh1 unchanged.
template <bool OUT_BF16>
__global__ __launch_bounds__(512, 1) void gemm_bt8(
    const __bf16* __restrict__ A, const __bf16* __restrict__ W,
    const float* __restrict__ bias, void* __restrict__ Cout,
    int M, int N, int K) {
  // [buf][A: 256 rows x 128 B | B: 128 rows x 128 B] = 2 x 48 KB
  __shared__ unsigned char lds[2][49152];
  const int t = threadIdx.x;
  const int lane = t & 63, wave = t >> 6;      // wave 0..7
  const int quad = lane >> 4, l16 = lane & 15;
  const int bid = blockIdx.x;                  // 256 blocks
  const int swz = (bid & 7) * 32 + (bid >> 3); // XCD-contiguous remap (256%8==0)
  const int m0 = (swz >> 4) * 256;
  const int n0 = (swz & 15) * 128;
  const int wm = (wave >> 1) * 64;             // 0,64,128,192
  const int wn = (wave & 1) * 64;              // 0,64

  // stage sources (pre-swizzled): LDS phys chunk p of row r holds global chunk
  // p ^ (r&7).  A = rounds 0..3 (rows 0..255), B = rounds 0..1 (rows 0..127).
  const __bf16* sA[4];
#pragma unroll
  for (int c = 0; c < 4; ++c) {
    int L = c * 512 + t;
    int row = L >> 3, p = L & 7;
    sA[c] = A + (size_t)(m0 + row) * K + ((p ^ (row & 7)) * 8);
  }
  const __bf16* sB[2];
#pragma unroll
  for (int c = 0; c < 2; ++c) {
    int L = c * 512 + t;
    int row = L >> 3, p = L & 7;
    sB[c] = W + (size_t)(n0 + row) * K + ((p ^ (row & 7)) * 8);
  }
  // read-side phys chunk per (kh, quad): (kh*4 + quad) ^ (l16&7)
  const int phk0 = (quad ^ (l16 & 7)) * 16;
  const int phk1 = ((4 + quad) ^ (l16 & 7)) * 16;

  f32x4 acc[4][4] = {};

  const int NT = K >> 6;  // 64-wide K-tiles

  // prologue: stage tile 0 into buf 0 (6 loads/thread, order A0..A3,B0,B1)
#pragma unroll
  for (int c = 0; c < 4; ++c)
    GLOAD_LDS16(sA[c], &lds[0][c * 8192 + wave * 1024]);
#pragma unroll
  for (int c = 0; c < 2; ++c)
    GLOAD_LDS16(sB[c], &lds[0][32768 + c * 8192 + wave * 1024]);

  for (int tt = 0; tt < NT; ++tt) {
    const int cur = tt & 1;
    const bool pf = (tt + 1 < NT);
    const int k1 = (tt + 1) << 6;
    unsigned char* nb = lds[cur ^ 1];
    const unsigned char* cb = lds[cur];

    bf16x8 af[4], bf01[2], bf23[2];

    // ---- P0: stage A0,A1(t+1); retire tile t's 6; read kh0 A + B[0,1] ----
    if (pf) {
      GLOAD_LDS16(sA[0] + k1, &nb[0 * 8192 + wave * 1024]);
      GLOAD_LDS16(sA[1] + k1, &nb[1 * 8192 + wave * 1024]);
      asm volatile("s_waitcnt vmcnt(2)" ::: "memory");
    } else {
      asm volatile("s_waitcnt vmcnt(0)" ::: "memory");
    }
    barrier_raw();
#pragma unroll
    for (int mt = 0; mt < 4; ++mt)
      af[mt] = *(const bf16x8*)&cb[(wm + mt * 16 + l16) * 128 + phk0];
#pragma unroll
    for (int nt = 0; nt < 2; ++nt)
      bf01[nt] = *(const bf16x8*)&cb[32768 + (wn + nt * 16 + l16) * 128 + phk0];
    __builtin_amdgcn_s_setprio(1);
#pragma unroll
    for (int mt = 0; mt < 4; ++mt)
#pragma unroll
      for (int nt = 0; nt < 2; ++nt)
        acc[mt][nt] = __builtin_amdgcn_mfma_f32_16x16x32_bf16(
            af[mt], bf01[nt], acc[mt][nt], 0, 0, 0);
    __builtin_amdgcn_s_setprio(0);

    // ---- P1: pre-barrier read kh0 B[2,3]; stage A2,A3(t+1) ----
#pragma unroll
    for (int nt = 0; nt < 2; ++nt)
      bf23[nt] =
          *(const bf16x8*)&cb[32768 + (wn + (nt + 2) * 16 + l16) * 128 + phk0];
    if (pf) {
      GLOAD_LDS16(sA[2] + k1, &nb[2 * 8192 + wave * 1024]);
      GLOAD_LDS16(sA[3] + k1, &nb[3 * 8192 + wave * 1024]);
    }
    barrier_raw();
    __builtin_amdgcn_s_setprio(1);
#pragma unroll
    for (int mt = 0; mt < 4; ++mt)
#pragma unroll
      for (int nt = 0; nt < 2; ++nt)
        acc[mt][nt + 2] = __builtin_amdgcn_mfma_f32_16x16x32_bf16(
            af[mt], bf23[nt], acc[mt][nt + 2], 0, 0, 0);
    __builtin_amdgcn_s_setprio(0);

    // ---- P2: pre-barrier read kh1 A + B[0,1]; stage B0(t+1) ----
#pragma unroll
    for (int mt = 0; mt < 4; ++mt)
      af[mt] = *(const bf16x8*)&cb[(wm + mt * 16 + l16) * 128 + phk1];
#pragma unroll
    for (int nt = 0; nt < 2; ++nt)
      bf01[nt] = *(const bf16x8*)&cb[32768 + (wn + nt * 16 + l16) * 128 + phk1];
    if (pf) {
      GLOAD_LDS16(sB[0] + k1, &nb[32768 + 0 * 8192 + wave * 1024]);
    }
    barrier_raw();
    __builtin_amdgcn_s_setprio(1);
#pragma unroll
    for (int mt = 0; mt < 4; ++mt)
#pragma unroll
      for (int nt = 0; nt < 2; ++nt)
        acc[mt][nt] = __builtin_amdgcn_mfma_f32_16x16x32_bf16(
            af[mt], bf01[nt], acc[mt][nt], 0, 0, 0);
    __builtin_amdgcn_s_setprio(0);

    // ---- P3: pre-barrier read kh1 B[2,3]; stage B1(t+1) ----
#pragma unroll
    for (int nt = 0; nt < 2; ++nt)
      bf23[nt] =
          *(const bf16x8*)&cb[32768 + (wn + (nt + 2) * 16 + l16) * 128 + phk1];
    if (pf) {
      GLOAD_LDS16(sB[1] + k1, &nb[32768 + 1 * 8192 + wave * 1024]);
    }
    barrier_raw();
    __builtin_amdgcn_s_setprio(1);
#pragma unroll
    for (int mt = 0; mt < 4; ++mt)
#pragma unroll
      for (int nt = 0; nt < 2; ++nt)
        acc[mt][nt + 2] = __builtin_amdgcn_mfma_f32_16x16x32_bf16(
            af[mt], bf23[nt], acc[mt][nt + 2], 0, 0, 0);
    __builtin_amdgcn_s_setprio(0);
    barrier_raw();  // fence: t+1's stage writes target the buffer we just read
  }

  // epilogue: C/D layout col=lane&15, row=quad*4+reg  [m89/m91 verified]
#pragma unroll
  for (int mt = 0; mt < 4; ++mt) {
#pragma unroll
    for (int nt = 0; nt < 4; ++nt) {
      int col = n0 + wn + nt * 16 + l16;
      float bv = bias[col];
#pragma unroll
      for (int r = 0; r < 4; ++r) {
        int row = m0 + wm + mt * 16 + quad * 4 + r;
        float v = acc[mt][nt][r] + bv;
        if constexpr (OUT_BF16)
          ((unsigned short*)Cout)[(size_t)row * N + col] = f2bf(v);
        else
          ((float*)Cout)[(size_t)row * N + col] = v;
      }
    }
  }
}

// ---------------- fp8 MX GEMM v10: C8[M][N] = e4m3( A8 @ W8^T + bias ) -----------
// BM=128, BN=128, BK=128, 256 threads (4 waves 2x2), dbuf 64 KB LDS
// -> 2 blocks/CU, counted vmcnt + chunk-XOR swizzle + setprio.
// Measured round 7: 49.4 -> <41.8 us (left top-5). Natural n-fastest grid.
__global__ __launch_bounds__(256, 2) void gemm_qk8(
    const unsigned char* __restrict__ A8, const unsigned char* __restrict__ W8,
    const float* __restrict__ bias, unsigned char* __restrict__ Cout,
    int M, int N, int K) {
  // [buf][A: 128 rows x 128 B | B: 128 rows x 128 B] = 2 x 32 KB
  __shared__ unsigned char lds[2][32768];
  const int t = threadIdx.x;
  const int lane = t & 63, wave = t >> 6;      // 0..3
  const int quad = lane >> 4, l16 = lane & 15;
  const int m0 = blockIdx.y * 128;
  const int n0 = blockIdx.x * 128;             // fastest -> XCD ~ n%8
  const int wm = (wave & 1) * 64, wn = (wave >> 1) * 64;

  // stage sources (pre-swizzled): LDS phys chunk p of row r holds global chunk
  // p ^ (r&7). 1024 chunks per matrix, 4 rounds of 256 threads each.
  const unsigned char* sA[4];
  const unsigned char* sB[4];
#pragma unroll
  for (int c = 0; c < 4; ++c) {
    int L = c * 256 + t;
    int row = L >> 3, p = L & 7;
    int sc = (p ^ (row & 7)) * 16;
    sA[c] = A8 + (size_t)(m0 + row) * K + sc;
    sB[c] = W8 + (size_t)(n0 + row) * K + sc;
  }
  const int p0 = (2 * quad) ^ (l16 & 7);   // phys chunk of logical chunk 2*quad

  f32x4 acc[4][4] = {};

  const int NT = K >> 7;  // 128-wide K-tiles (16)

  // prologue: stage tile 0 into buf 0 (8 loads/thread)
#pragma unroll
  for (int c = 0; c < 4; ++c)
    GLOAD_LDS16(sA[c], &lds[0][(c * 256 + wave * 64) * 16]);
#pragma unroll
  for (int c = 0; c < 4; ++c)
    GLOAD_LDS16(sB[c], &lds[0][16384 + (c * 256 + wave * 64) * 16]);

  for (int tt = 0; tt < NT; ++tt) {
    const int cur = tt & 1;
    const bool pf = (tt + 1 < NT);
    const int k1 = (tt + 1) << 7;

    // ---- phase 0: issue A(t+1), retire tile t's loads, compute nt 0,1 ----
    if (pf) {
#pragma unroll
      for (int c = 0; c < 4; ++c)
        GLOAD_LDS16(sA[c] + k1, &lds[cur ^ 1][(c * 256 + wave * 64) * 16]);
      asm volatile("s_waitcnt vmcnt(4)" ::: "memory");  // tile-t's 8 landed
    } else {
      asm volatile("s_waitcnt vmcnt(0)" ::: "memory");
    }
    barrier_raw();
    i32x8 af[4];
    {
#pragma unroll
      for (int mt = 0; mt < 4; ++mt) {
        int ra = (wm + mt * 16 + l16) * 128 + p0 * 16;
        ((i32x4*)&af[mt])[0] = *(const i32x4*)&lds[cur][ra];
        ((i32x4*)&af[mt])[1] = *(const i32x4*)&lds[cur][ra ^ 16];
      }
      i32x8 bv[2];
#pragma unroll
      for (int nt = 0; nt < 2; ++nt) {
        int rb = 16384 + (wn + nt * 16 + l16) * 128 + p0 * 16;
        ((i32x4*)&bv[nt])[0] = *(const i32x4*)&lds[cur][rb];
        ((i32x4*)&bv[nt])[1] = *(const i32x4*)&lds[cur][rb ^ 16];
      }
      __builtin_amdgcn_s_setprio(1);
#pragma unroll
      for (int mt = 0; mt < 4; ++mt)
#pragma unroll
        for (int nt = 0; nt < 2; ++nt)
          acc[mt][nt] = __builtin_amdgcn_mfma_scale_f32_16x16x128_f8f6f4(
              af[mt], bv[nt], acc[mt][nt], 0, 0, 0, 127, 0, 127);
      __builtin_amdgcn_s_setprio(0);
    }

    // ---- phase 1: issue B(t+1), compute nt 2,3 ----
    if (pf) {
#pragma unroll
      for (int c = 0; c < 4; ++c)
        GLOAD_LDS16(sB[c] + k1, &lds[cur ^ 1][16384 + (c * 256 + wave * 64) * 16]);
    }
    barrier_raw();
    {
      i32x8 bv[2];
#pragma unroll
      for (int nt = 0; nt < 2; ++nt) {
        int rb = 16384 + (wn + (nt + 2) * 16 + l16) * 128 + p0 * 16;
        ((i32x4*)&bv[nt])[0] = *(const i32x4*)&lds[cur][rb];
        ((i32x4*)&bv[nt])[1] = *(const i32x4*)&lds[cur][rb ^ 16];
      }
      __builtin_amdgcn_s_setprio(1);
#pragma unroll
      for (int mt = 0; mt < 4; ++mt)
#pragma unroll
        for (int nt = 0; nt < 2; ++nt)
          acc[mt][nt + 2] = __builtin_amdgcn_mfma_scale_f32_16x16x128_f8f6f4(
              af[mt], bv[nt], acc[mt][nt + 2], 0, 0, 0, 127, 0, 127);
      __builtin_amdgcn_s_setprio(0);
    }
    barrier_raw();  // all waves done reading buf[cur] before tt+1 overwrites it
  }

  // epilogue: C/D layout shape-determined, same as 16x16x32 [m121-m128]
#pragma unroll
  for (int mt = 0; mt < 4; ++mt) {
#pragma unroll
    for (int nt = 0; nt < 4; ++nt) {
      int col = n0 + wn + nt * 16 + l16;
      float bv = bias[col];
#pragma unroll
      for (int r = 0; r < 4; ++r) {
        int row = m0 + wm + mt * 16 + quad * 4 + r;
        Cout[(size_t)row * N + col] = f2e4m3(acc[mt][nt][r] + bv);
      }
    }
  }
}

// ---------------- QK^T upper-triangle exp row-sums + diagonal (MX fp8) ----------------
//  - one mfma_scale 16x16x128 per 16x16 score tile (K=128 = whole head-dim)
//  - waves split by COLUMN (each wave: 32 cols x all 64 rows)
//  - chunk-XOR swizzle staged via pre-swizzled global source
//  - diagonal/masked logic peeled into the first j-tile only
//  - 2-phase double-buffered staging; 2-way j-split (grid.x = 32)
__global__ __launch_bounds__(256, 4) void qk_rowsum8(
    const unsigned char* __restrict__ q8, const unsigned char* __restrict__ k8,
    float* __restrict__ denomA, float* __restrict__ denomB,
    float* __restrict__ diag) {
  __shared__ unsigned char lK[2][128 * 128];  // 32 KB double-buffered
  __shared__ float redS[4][64];
  __shared__ float redD[4][64];
  const int t = threadIdx.x;
  const int lane = t & 63, wave = t >> 6;
  const int quad = lane >> 4, l16 = lane & 15;
  const int bh = blockIdx.y;
  const int b = bh >> 4, h = bh & 15;
  const int pair = blockIdx.x >> 1;       // 0..15 (work-balanced i-tile pair)
  const int half = blockIdx.x & 1;        // j-split: tiles with k%2==half
  const float C = 0.03187935771f;         // (1/sqrt(2048)) * log2(e)
  const f32x4 fz = {0.f, 0.f, 0.f, 0.f};

  // staging source offsets (swizzled): LDS chunk L holds global chunk (L&7)^(row&7)
  int soff[4];
#pragma unroll
  for (int c = 0; c < 4; ++c) {
    int L = c * 256 + t;
    int row = L >> 3, p = L & 7;
    soff[c] = row * QKN + ((p ^ (row & 7)) * 16);
  }
  // LDS read byte offsets: B-row r = wave*32 + nt*16 + l16, phys chunk (2q)^(l16&7)
  const int p0 = (2 * quad) ^ (l16 & 7);
  int bo[2];
#pragma unroll
  for (int nt = 0; nt < 2; ++nt)
    bo[nt] = (wave * 32 + nt * 16 + l16) * 128 + p0 * 16;

  const unsigned char* kbase = k8 + (size_t)(b * SS) * QKN + h * HDIM;

  for (int sub = 0; sub < 2; ++sub) {
    const int tile = (sub == 0) ? pair : 31 - pair;
    const int i0 = tile * 64;
    const int jbase = i0 & ~127;
    const int ntile = (SS - jbase) >> 7;

    // A fragments: Q rows i0 + mt*16 + l16, k-bytes quad*32 (held in regs)
    i32x8 af[4];
    {
      const unsigned char* qbase =
          q8 + (size_t)(b * SS + i0 + l16) * QKN + h * HDIM + quad * 32;
#pragma unroll
      for (int mt = 0; mt < 4; ++mt)
        af[mt] = *(const i32x8*)(qbase + (size_t)(mt * 16) * QKN);
    }

    float rowacc[4][4] = {};

    int kidx = half;
    if (kidx < ntile) {
      {  // prologue: stage first tile into buf 0
        const unsigned char* src = kbase + (size_t)(jbase + kidx * 128) * QKN;
#pragma unroll
        for (int c = 0; c < 4; ++c)
          GLOAD_LDS16(src + soff[c], &lK[0][(c * 256 + wave * 64) * 16]);
      }
      asm volatile("s_waitcnt vmcnt(0)" ::: "memory");
      __syncthreads();
      int cur = 0;
      for (; kidx < ntile; kidx += 2, cur ^= 1) {
        if (kidx + 2 < ntile) {  // issue next-tile stage before compute
          const unsigned char* src =
              kbase + (size_t)(jbase + (kidx + 2) * 128) * QKN;
#pragma unroll
          for (int c = 0; c < 4; ++c)
            GLOAD_LDS16(src + soff[c], &lK[cur ^ 1][(c * 256 + wave * 64) * 16]);
        }
        const unsigned char* lkc = lK[cur];
        const int j0 = jbase + kidx * 128;
        if (kidx == 0) {
          // diagonal/masked tile (always half 0's first tile)
          float dloc[4][4] = {};
#pragma unroll
          for (int nt = 0; nt < 2; ++nt) {
            i32x8 bf;
            ((i32x4*)&bf)[0] = *(const i32x4*)(lkc + bo[nt]);
            ((i32x4*)&bf)[1] = *(const i32x4*)(lkc + (bo[nt] ^ 16));
            f32x4 acc[4];
#pragma unroll
            for (int mt = 0; mt < 4; ++mt)
              acc[mt] = __builtin_amdgcn_mfma_scale_f32_16x16x128_f8f6f4(
                  af[mt], bf, fz, 0, 0, 0, 127, 0, 127);
            const int colg = j0 + wave * 32 + nt * 16 + l16;
#pragma unroll
            for (int mt = 0; mt < 4; ++mt)
#pragma unroll
              for (int r = 0; r < 4; ++r) {
                int rg = i0 + mt * 16 + quad * 4 + r;
                float e = (colg >= rg)
                              ? __builtin_amdgcn_exp2f(acc[mt][r] * C) : 0.f;
                rowacc[mt][r] += e;
                if (colg == rg) dloc[mt][r] = e;
              }
          }
          // reduce + stash diag immediately (frees dloc registers)
#pragma unroll
          for (int mt = 0; mt < 4; ++mt)
#pragma unroll
            for (int r = 0; r < 4; ++r) {
              float d = dloc[mt][r];
#pragma unroll
              for (int off = 1; off < 16; off <<= 1) d += __shfl_xor(d, off, 64);
              if (l16 == 0) redD[wave][mt * 16 + quad * 4 + r] = d;
            }
        } else {
          // unmasked: all cols > all rows
#pragma unroll
          for (int nt = 0; nt < 2; ++nt) {
            i32x8 bf;
            ((i32x4*)&bf)[0] = *(const i32x4*)(lkc + bo[nt]);
            ((i32x4*)&bf)[1] = *(const i32x4*)(lkc + (bo[nt] ^ 16));
            f32x4 acc[4];
#pragma unroll
            for (int mt = 0; mt < 4; ++mt)
              acc[mt] = __builtin_amdgcn_mfma_scale_f32_16x16x128_f8f6f4(
                  af[mt], bf, fz, 0, 0, 0, 127, 0, 127);
#pragma unroll
            for (int mt = 0; mt < 4; ++mt)
#pragma unroll
              for (int r = 0; r < 4; ++r)
                rowacc[mt][r] += __builtin_amdgcn_exp2f(acc[mt][r] * C);
          }
        }
        asm volatile("s_waitcnt vmcnt(0)" ::: "memory");
        __syncthreads();
      }
    }

    // cross-wave reduction (redS/redD reused across subs -> barrier first)
    __syncthreads();
#pragma unroll
    for (int mt = 0; mt < 4; ++mt)
#pragma unroll
      for (int r = 0; r < 4; ++r) {
        float s = rowacc[mt][r];
#pragma unroll
        for (int off = 1; off < 16; off <<= 1) s += __shfl_xor(s, off, 64);
        if (l16 == 0) redS[wave][mt * 16 + quad * 4 + r] = s;
      }
    __syncthreads();
    if (t < 64) {
      const int rg = i0 + t;
      float s = redS[0][t] + redS[1][t] + redS[2][t] + redS[3][t];
      if (half == 0) {
        denomA[bh * SS + rg] = (float)rg + s;
        diag[bh * SS + rg] = redD[0][t] + redD[1][t] + redD[2][t] + redD[3][t];
      } else {
        denomB[bh * SS + rg] = s;
      }
    }
  }
}

// ---------------- V prefix-scan, two-pass, 16B/lane ----------------
// v is a dedicated [MTOK][DD] bf16 buffer.
__global__ void scan_pass1(const __bf16* __restrict__ v0,
                           float* __restrict__ csum) {
  int blk = blockIdx.x;
  int bh = blk >> 4, c = blk & 15;
  int b = bh >> 4, h = bh & 15;
  int t = threadIdx.x;
  int rs = t >> 4, dg = t & 15;
  const unsigned short* base = (const unsigned short*)v0 +
      (size_t)(b * SS + c * 128 + rs * 8) * DD + h * HDIM + dg * 8;
  float s[8] = {0.f, 0.f, 0.f, 0.f, 0.f, 0.f, 0.f, 0.f};
#pragma unroll
  for (int i = 0; i < 8; ++i) {
    uint4 u = *(const uint4*)(base + (size_t)i * DD);
    const unsigned short* us = (const unsigned short*)&u;
#pragma unroll
    for (int j = 0; j < 8; ++j) s[j] += bf2f(us[j]);
  }
  __shared__ float red[16 * 128];
#pragma unroll
  for (int j = 0; j < 8; ++j) red[rs * 128 + dg * 8 + j] = s[j];
  __syncthreads();
  for (int st = 8; st >= 1; st >>= 1) {
    if (rs < st) {
#pragma unroll
      for (int j = 0; j < 8; ++j)
        red[rs * 128 + dg * 8 + j] += red[(rs + st) * 128 + dg * 8 + j];
    }
    __syncthreads();
  }
  if (rs == 0) {
#pragma unroll
    for (int j = 0; j < 8; ++j)
      csum[(size_t)blk * 128 + dg * 8 + j] = red[dg * 8 + j];
  }
}

__global__ void scan_pass2(const __bf16* __restrict__ v0,
                           const float* __restrict__ csum,
                           const float* __restrict__ denomA,
                           const float* __restrict__ denomB,
                           const float* __restrict__ diag,
                           unsigned short* __restrict__ ctx) {
  int blk = blockIdx.x;
  int bh = blk >> 4, c = blk & 15;
  int b = bh >> 4, h = bh & 15;
  int t = threadIdx.x;
  int rs = t >> 4, dg = t & 15;
  const unsigned short* vbase = (const unsigned short*)v0 +
      (size_t)(b * SS + c * 128 + rs * 8) * DD + h * HDIM + dg * 8;
  float vrow[8][8];
  float ls[8] = {0.f, 0.f, 0.f, 0.f, 0.f, 0.f, 0.f, 0.f};
#pragma unroll
  for (int i = 0; i < 8; ++i) {
    uint4 u = *(const uint4*)(vbase + (size_t)i * DD);
    const unsigned short* us = (const unsigned short*)&u;
#pragma unroll
    for (int j = 0; j < 8; ++j) {
      vrow[i][j] = bf2f(us[j]);
      ls[j] += vrow[i][j];
    }
  }
  __shared__ float red[16 * 128];
#pragma unroll
  for (int j = 0; j < 8; ++j) red[rs * 128 + dg * 8 + j] = ls[j];
  __syncthreads();

  float pre[8] = {0.f, 0.f, 0.f, 0.f, 0.f, 0.f, 0.f, 0.f};
  for (int cc = 0; cc < c; ++cc) {
    const float* cp = csum + (size_t)(bh * 16 + cc) * 128 + dg * 8;
#pragma unroll
    for (int j = 0; j < 8; ++j) pre[j] += cp[j];
  }
  for (int ss2 = 0; ss2 < rs; ++ss2) {
#pragma unroll
    for (int j = 0; j < 8; ++j) pre[j] += red[ss2 * 128 + dg * 8 + j];
  }

  int row0 = c * 128 + rs * 8;
  unsigned short* obase =
      ctx + (size_t)(b * SS + row0) * DD + h * HDIM + dg * 8;
  const float* dnA = denomA + bh * SS + row0;
  const float* dnB = denomB + bh * SS + row0;
  const float* dgp = diag + bh * SS + row0;
#pragma unroll
  for (int i = 0; i < 8; ++i) {
    float inv = 1.0f / (dnA[i] + dnB[i]);
    float dv = dgp[i];
    unsigned short o[8];
#pragma unroll
    for (int j = 0; j < 8; ++j) {
      float val = (pre[j] + dv * vrow[i][j]) * inv;
      o[j] = f2bf(val);
      pre[j] += vrow[i][j];
    }
    *(uint4*)(obase + (size_t)i * DD) = *(const uint4*)o;
  }
}

extern "C" void kernel_launch(void* const* d_in, const int* in_sizes, int n_in,
                              void* d_out, int out_size, void* d_ws, size_t ws_size,
                              hipStream_t stream) {
  (void)in_sizes; (void)n_in; (void)out_size; (void)ws_size;
  const float* x    = (const float*)d_in[0];
  const float* wq_w = (const float*)d_in[1];
  const float* wq_b = (const float*)d_in[2];
  const float* wk_w = (const float*)d_in[3];
  const float* wk_b = (const float*)d_in[4];
  const float* wv_w = (const float*)d_in[5];
  const float* wv_b = (const float*)d_in[6];
  const float* wo_w = (const float*)d_in[7];
  const float* wo_b = (const float*)d_in[8];

  char* ws = (char*)d_ws;
  size_t off = 0;
  auto alloc = [&](size_t bytes) {
    char* p = ws + off;
    off += (bytes + 255) & ~(size_t)255;
    return p;
  };
  unsigned short* xb   = (unsigned short*)alloc((size_t)MTOK * DD * 2);    // 16 MB
  unsigned char*  x8   = (unsigned char*)alloc((size_t)MTOK * DD);         // 8 MB
  unsigned char*  wqk8 = (unsigned char*)alloc((size_t)2 * DD * DD);       // 8 MB
  unsigned short* wvo  = (unsigned short*)alloc((size_t)2 * DD * DD * 2);  // 16 MB (wv | wo)
  unsigned char*  qk8  = (unsigned char*)alloc((size_t)MTOK * QKN);        // 16 MB
  unsigned short* v    = (unsigned short*)alloc((size_t)MTOK * DD * 2);    // 16 MB
  unsigned short* ctx  = (unsigned short*)alloc((size_t)MTOK * DD * 2);    // 16 MB
  float* biasqk = (float*)alloc((size_t)2 * DD * 4);
  float* denomA = (float*)alloc((size_t)BHH * SS * 4);
  float* denomB = (float*)alloc((size_t)BHH * SS * 4);
  float* diag   = (float*)alloc((size_t)BHH * SS * 4);
  float* csum   = (float*)alloc((size_t)BHH * NCHUNK * 128 * 4);

  // 1) converts (x-convert + fused weight/bias converts)
  {
    int n4 = MTOK * DD / 4;
    cvt_x_dual<<<n4 / 256, 256, 0, stream>>>(x, xb, (unsigned int*)x8, n4);
    cvt_w_all<<<16400, 256, 0, stream>>>(wq_w, wk_w, wv_w, wo_w, wq_b, wk_b,
                                         (unsigned int*)wqk8, wvo, biasqk);
  }

  // 2) QK projection, MX-fp8 (2 blocks/CU + counted vmcnt, n-fast grid):
  //    [4096,2048] x [4096,2048]^T -> qk8 [4096][4096] e4m3
  gemm_qk8<<<dim3(QKN / 128, MTOK / 128), 256, 0, stream>>>(
      x8, wqk8, biasqk, qk8, MTOK, QKN, DD);

  // 3) V projection in bf16 -> v [4096][2048]  (4-fine-phase GEMM, BM=256 BN=128)
  gemm_bt8<true><<<(MTOK / 256) * (DD / 128), 512, 0, stream>>>(
      (const __bf16*)xb, (const __bf16*)wvo, wv_b, v, MTOK, DD, DD);

  // 4) denominators + diagonal exps (MX fp8 MFMA, paired i-tiles, 2-way j-split)
  qk_rowsum8<<<dim3(32, BHH), 256, 0, stream>>>(
      qk8,            // q at col 0
      qk8 + DD,       // k at col 2048
      denomA, denomB, diag);

  // 5) V scan -> ctx
  scan_pass1<<<BHH * NCHUNK, 256, 0, stream>>>((const __bf16*)v, csum);
  scan_pass2<<<BHH * NCHUNK, 256, 0, stream>>>((const __bf16*)v, csum,
                                               denomA, denomB, diag, ctx);

  // 6) output projection: [4096,2048] x [2048,2048]^T -> d_out fp32
  gemm_bt8<false><<<(MTOK / 256) * (DD / 128), 512, 0, stream>>>(
      (const __bf16*)ctx, (const __bf16*)(wvo + (size_t)DD * DD), wo_b,
      d_out, MTOK, DD, DD);
}

// Round 10
// 310.658 us; speedup vs baseline: 1.0330x; 1.0125x over previous
//
#include <hip/hip_runtime.h>

// Problem constants
#define BB 2
#define SS 2048
#define DD 2048
#define HH 16
#define HDIM 128
#define MTOK (BB*SS)     // 4096 token rows
#define BHH (BB*HH)      // 32 (b,h) pairs
#define NCHUNK 16        // scan chunks per (b,h): 2048/128
#define QKN (2*DD)       // fp8 qk row stride (q cols 0..2047, k cols 2048..4095)

typedef __attribute__((ext_vector_type(8))) __bf16 bf16x8;
typedef __attribute__((ext_vector_type(4))) float f32x4;
typedef __attribute__((ext_vector_type(8))) int i32x8;
typedef __attribute__((ext_vector_type(4))) int i32x4;

__device__ __forceinline__ unsigned short f2bf(float f) {
  unsigned u = __float_as_uint(f);
  u += 0x7FFFu + ((u >> 16) & 1u);   // RNE
  return (unsigned short)(u >> 16);
}
__device__ __forceinline__ float bf2f(unsigned short s) {
  return __uint_as_float(((unsigned)s) << 16);
}
__device__ __forceinline__ unsigned char f2e4m3(float f) {
  // HW convert, OCP e4m3fn on gfx950, saturating
  int pk = __builtin_amdgcn_cvt_pk_fp8_f32(f, f, 0, false);
  return (unsigned char)(pk & 0xFF);
}

// async global->LDS, 16B per lane; dst must be wave-uniform base (HW adds lane*16)
#define GLOAD_LDS16(src, dst)                                                   \
  __builtin_amdgcn_global_load_lds(                                             \
      (const void __attribute__((address_space(1)))*)(src),                     \
      (void __attribute__((address_space(3)))*)(dst), 16, 0, 0)

__device__ __forceinline__ void barrier_raw() {
  asm volatile("" ::: "memory");
  __builtin_amdgcn_s_barrier();
  asm volatile("" ::: "memory");
}

// ---------------- converts ----------------
// x -> bf16 (for V gemm) and fp8 (for QK gemm) in one pass
__global__ void cvt_x_dual(const float* __restrict__ in,
                           unsigned short* __restrict__ outb,
                           unsigned int* __restrict__ out8, int n4) {
  int i = blockIdx.x * blockDim.x + threadIdx.x;
  if (i < n4) {
    float4 v = ((const float4*)in)[i];
    ushort4 o;
    o.x = f2bf(v.x); o.y = f2bf(v.y); o.z = f2bf(v.z); o.w = f2bf(v.w);
    ((ushort4*)outb)[i] = o;
    int p0 = __builtin_amdgcn_cvt_pk_fp8_f32(v.x, v.y, 0, false);
    int p1 = __builtin_amdgcn_cvt_pk_fp8_f32(v.z, v.w, 0, false);
    out8[i] = (unsigned)(p0 & 0xFFFF) | ((unsigned)(p1 & 0xFFFF) << 16);
  }
}

// fused weight converts: wq,wk -> fp8 [2*DD][DD]; wv,wo -> bf16 (wv|wo); bias concat
// region-branched grid: [0,8192) fp8, [8192,16384) bf16, [16384,16400) bias
__global__ void cvt_w_all(const float* __restrict__ wq, const float* __restrict__ wk,
                          const float* __restrict__ wv, const float* __restrict__ wo,
                          const float* __restrict__ wqb, const float* __restrict__ wkb,
                          unsigned int* __restrict__ out8,
                          unsigned short* __restrict__ outb,
                          float* __restrict__ biasqk) {
  int blk = blockIdx.x;
  int tid = threadIdx.x;
  if (blk < 8192) {
    int i = blk * 256 + tid;              // < 2<<20
    int sel = i >> 20, r = i & 0xFFFFF;   // DD*DD/4 == 1<<20
    const float* src = sel == 0 ? wq : wk;
    float4 v = ((const float4*)src)[r];
    int p0 = __builtin_amdgcn_cvt_pk_fp8_f32(v.x, v.y, 0, false);
    int p1 = __builtin_amdgcn_cvt_pk_fp8_f32(v.z, v.w, 0, false);
    out8[i] = (unsigned)(p0 & 0xFFFF) | ((unsigned)(p1 & 0xFFFF) << 16);
  } else if (blk < 16384) {
    int i = (blk - 8192) * 256 + tid;
    int sel = i >> 20, r = i & 0xFFFFF;
    const float* src = sel == 0 ? wv : wo;
    float4 v = ((const float4*)src)[r];
    ushort4 o;
    o.x = f2bf(v.x); o.y = f2bf(v.y); o.z = f2bf(v.z); o.w = f2bf(v.w);
    ((ushort4*)outb)[i] = o;
  } else {
    int i = (blk - 16384) * 256 + tid;    // < 4096 = 2*DD
    biasqk[i] = (i < DD) ? wqb[i] : wkb[i - DD];
  }
}

// ---------------- bf16 GEMM v11: C[M][N] = A[M][K] @ W[N][K]^T + bias[N] ---------
// Round-9 post-mortem: at BM=256 / 1 block/CU, BOTH the coarse 2-phase and the
// 4-fine-phase schedule land at 42 us, MfmaUtil 30% -> schedule shape is not the
// limiter at 1 block/CU; occupancy is (same finding as fp8 in round 7, where
// 128^2 + 2 blocks/CU + counted vmcnt took 49.4 -> <41.8). v11 = exact port of
// the winning fp8 v10 geometry+schedule to bf16:
//   BM=128, BN=128, BK=64, 256 threads (4 waves 2x2, 64x64 out/wave),
//   dbuf 64 KB LDS -> 2 blocks/CU. A 64-elem bf16 row = 128 B = 8x16B chunks,
//   identical addressing to fp8's 128-elem rows.
//   Phase 0 {issue 4xA(t+1); vmcnt(4); barrier; read kh0 frags; 16 MFMA}
//   Phase 1 {issue 4xB(t+1); barrier; read kh1 frags; 16 MFMA}; trailing barrier.
//   vmcnt: 8 loads/tile; at P0 outstanding = 8 old + 4 new -> vmcnt(4) retires
//   exactly tile t's 8. K order kh0->kh1 per element unchanged (bit-identical).
//   Natural 2D grid (16 n, 32 m) = 512 blocks = 2/CU; per-XCD B set = 2 panels
//   = 1 MB, L2-resident (x%8 == xcd for all y since 16y = 0 mod 8).
template <bool OUT_BF16>
__global__ __launch_bounds__(256, 2) void gemm_bt8(
    const __bf16* __restrict__ A, const __bf16* __restrict__ W,
    const float* __restrict__ bias, void* __restrict__ Cout,
    int M, int N, int K) {
  // [buf][A: 128 rows x 128 B | B: 128 rows x 128 B] = 2 x 32 KB
  __shared__ unsigned char lds[2][32768];
  const int t = threadIdx.x;
  const int lane = t & 63, wave = t >> 6;      // 0..3
  const int quad = lane >> 4, l16 = lane & 15;
  const int m0 = blockIdx.y * 128;
  const int n0 = blockIdx.x * 128;             // fastest -> XCD ~ n%8
  const int wm = (wave & 1) * 64, wn = (wave >> 1) * 64;

  // stage sources (pre-swizzled): LDS phys chunk p of row r holds global chunk
  // p ^ (r&7). 1024 chunks (16B) per matrix per K-tile, 4 rounds of 256 threads.
  const __bf16* sA[4];
  const __bf16* sB[4];
#pragma unroll
  for (int c = 0; c < 4; ++c) {
    int L = c * 256 + t;
    int row = L >> 3, p = L & 7;
    int sc = (p ^ (row & 7)) * 8;              // 8 bf16 = 16 B
    sA[c] = A + (size_t)(m0 + row) * K + sc;
    sB[c] = W + (size_t)(n0 + row) * K + sc;
  }
  // read-side phys chunk per (kh, quad): (kh*4 + quad) ^ (l16&7)
  const int phk0 = (quad ^ (l16 & 7)) * 16;
  const int phk1 = ((4 + quad) ^ (l16 & 7)) * 16;

  f32x4 acc[4][4] = {};

  const int NT = K >> 6;  // 64-wide K-tiles (32)

  // prologue: stage tile 0 into buf 0 (8 loads/thread)
#pragma unroll
  for (int c = 0; c < 4; ++c)
    GLOAD_LDS16(sA[c], &lds[0][(c * 256 + wave * 64) * 16]);
#pragma unroll
  for (int c = 0; c < 4; ++c)
    GLOAD_LDS16(sB[c], &lds[0][16384 + (c * 256 + wave * 64) * 16]);

  for (int tt = 0; tt < NT; ++tt) {
    const int cur = tt & 1;
    const bool pf = (tt + 1 < NT);
    const int k1 = (tt + 1) << 6;

    // ---- phase 0: issue A(t+1), retire tile t's loads, compute kh0 ----
    if (pf) {
#pragma unroll
      for (int c = 0; c < 4; ++c)
        GLOAD_LDS16(sA[c] + k1, &lds[cur ^ 1][(c * 256 + wave * 64) * 16]);
      asm volatile("s_waitcnt vmcnt(4)" ::: "memory");  // tile-t's 8 landed
    } else {
      asm volatile("s_waitcnt vmcnt(0)" ::: "memory");
    }
    barrier_raw();
    {
      bf16x8 af[4], bfv[4];
#pragma unroll
      for (int mt = 0; mt < 4; ++mt)
        af[mt] = *(const bf16x8*)&lds[cur][(wm + mt * 16 + l16) * 128 + phk0];
#pragma unroll
      for (int nt = 0; nt < 4; ++nt)
        bfv[nt] =
            *(const bf16x8*)&lds[cur][16384 + (wn + nt * 16 + l16) * 128 + phk0];
      __builtin_amdgcn_s_setprio(1);
#pragma unroll
      for (int mt = 0; mt < 4; ++mt)
#pragma unroll
        for (int nt = 0; nt < 4; ++nt)
          acc[mt][nt] = __builtin_amdgcn_mfma_f32_16x16x32_bf16(
              af[mt], bfv[nt], acc[mt][nt], 0, 0, 0);
      __builtin_amdgcn_s_setprio(0);
    }

    // ---- phase 1: issue B(t+1), compute kh1 ----
    if (pf) {
#pragma unroll
      for (int c = 0; c < 4; ++c)
        GLOAD_LDS16(sB[c] + k1, &lds[cur ^ 1][16384 + (c * 256 + wave * 64) * 16]);
    }
    barrier_raw();
    {
      bf16x8 af[4], bfv[4];
#pragma unroll
      for (int mt = 0; mt < 4; ++mt)
        af[mt] = *(const bf16x8*)&lds[cur][(wm + mt * 16 + l16) * 128 + phk1];
#pragma unroll
      for (int nt = 0; nt < 4; ++nt)
        bfv[nt] =
            *(const bf16x8*)&lds[cur][16384 + (wn + nt * 16 + l16) * 128 + phk1];
      __builtin_amdgcn_s_setprio(1);
#pragma unroll
      for (int mt = 0; mt < 4; ++mt)
#pragma unroll
        for (int nt = 0; nt < 4; ++nt)
          acc[mt][nt] = __builtin_amdgcn_mfma_f32_16x16x32_bf16(
              af[mt], bfv[nt], acc[mt][nt], 0, 0, 0);
      __builtin_amdgcn_s_setprio(0);
    }
    barrier_raw();  // all waves done reading buf[cur] before tt+1 overwrites it
  }

  // epilogue: C/D layout col=lane&15, row=quad*4+reg  [m89/m91 verified]
#pragma unroll
  for (int mt = 0; mt < 4; ++mt) {
#pragma unroll
    for (int nt = 0; nt < 4; ++nt) {
      int col = n0 + wn + nt * 16 + l16;
      float bv = bias[col];
#pragma unroll
      for (int r = 0; r < 4; ++r) {
        int row = m0 + wm + mt * 16 + quad * 4 + r;
        float v = acc[mt][nt][r] + bv;
        if constexpr (OUT_BF16)
          ((unsigned short*)Cout)[(size_t)row * N + col] = f2bf(v);
        else
          ((float*)Cout)[(size_t)row * N + col] = v;
      }
    }
  }
}

// ---------------- fp8 MX GEMM v10: C8[M][N] = e4m3( A8 @ W8^T + bias ) -----------
// BM=128, BN=128, BK=128, 256 threads (4 waves 2x2), dbuf 64 KB LDS
// -> 2 blocks/CU, counted vmcnt + chunk-XOR swizzle + setprio.
// Measured round 7: 49.4 -> <41.8 us (left top-5). Natural n-fastest grid.
__global__ __launch_bounds__(256, 2) void gemm_qk8(
    const unsigned char* __restrict__ A8, const unsigned char* __restrict__ W8,
    const float* __restrict__ bias, unsigned char* __restrict__ Cout,
    int M, int N, int K) {
  // [buf][A: 128 rows x 128 B | B: 128 rows x 128 B] = 2 x 32 KB
  __shared__ unsigned char lds[2][32768];
  const int t = threadIdx.x;
  const int lane = t & 63, wave = t >> 6;      // 0..3
  const int quad = lane >> 4, l16 = lane & 15;
  const int m0 = blockIdx.y * 128;
  const int n0 = blockIdx.x * 128;             // fastest -> XCD ~ n%8
  const int wm = (wave & 1) * 64, wn = (wave >> 1) * 64;

  // stage sources (pre-swizzled): LDS phys chunk p of row r holds global chunk
  // p ^ (r&7). 1024 chunks per matrix, 4 rounds of 256 threads each.
  const unsigned char* sA[4];
  const unsigned char* sB[4];
#pragma unroll
  for (int c = 0; c < 4; ++c) {
    int L = c * 256 + t;
    int row = L >> 3, p = L & 7;
    int sc = (p ^ (row & 7)) * 16;
    sA[c] = A8 + (size_t)(m0 + row) * K + sc;
    sB[c] = W8 + (size_t)(n0 + row) * K + sc;
  }
  const int p0 = (2 * quad) ^ (l16 & 7);   // phys chunk of logical chunk 2*quad

  f32x4 acc[4][4] = {};

  const int NT = K >> 7;  // 128-wide K-tiles (16)

  // prologue: stage tile 0 into buf 0 (8 loads/thread)
#pragma unroll
  for (int c = 0; c < 4; ++c)
    GLOAD_LDS16(sA[c], &lds[0][(c * 256 + wave * 64) * 16]);
#pragma unroll
  for (int c = 0; c < 4; ++c)
    GLOAD_LDS16(sB[c], &lds[0][16384 + (c * 256 + wave * 64) * 16]);

  for (int tt = 0; tt < NT; ++tt) {
    const int cur = tt & 1;
    const bool pf = (tt + 1 < NT);
    const int k1 = (tt + 1) << 7;

    // ---- phase 0: issue A(t+1), retire tile t's loads, compute nt 0,1 ----
    if (pf) {
#pragma unroll
      for (int c = 0; c < 4; ++c)
        GLOAD_LDS16(sA[c] + k1, &lds[cur ^ 1][(c * 256 + wave * 64) * 16]);
      asm volatile("s_waitcnt vmcnt(4)" ::: "memory");  // tile-t's 8 landed
    } else {
      asm volatile("s_waitcnt vmcnt(0)" ::: "memory");
    }
    barrier_raw();
    i32x8 af[4];
    {
#pragma unroll
      for (int mt = 0; mt < 4; ++mt) {
        int ra = (wm + mt * 16 + l16) * 128 + p0 * 16;
        ((i32x4*)&af[mt])[0] = *(const i32x4*)&lds[cur][ra];
        ((i32x4*)&af[mt])[1] = *(const i32x4*)&lds[cur][ra ^ 16];
      }
      i32x8 bv[2];
#pragma unroll
      for (int nt = 0; nt < 2; ++nt) {
        int rb = 16384 + (wn + nt * 16 + l16) * 128 + p0 * 16;
        ((i32x4*)&bv[nt])[0] = *(const i32x4*)&lds[cur][rb];
        ((i32x4*)&bv[nt])[1] = *(const i32x4*)&lds[cur][rb ^ 16];
      }
      __builtin_amdgcn_s_setprio(1);
#pragma unroll
      for (int mt = 0; mt < 4; ++mt)
#pragma unroll
        for (int nt = 0; nt < 2; ++nt)
          acc[mt][nt] = __builtin_amdgcn_mfma_scale_f32_16x16x128_f8f6f4(
              af[mt], bv[nt], acc[mt][nt], 0, 0, 0, 127, 0, 127);
      __builtin_amdgcn_s_setprio(0);
    }

    // ---- phase 1: issue B(t+1), compute nt 2,3 ----
    if (pf) {
#pragma unroll
      for (int c = 0; c < 4; ++c)
        GLOAD_LDS16(sB[c] + k1, &lds[cur ^ 1][16384 + (c * 256 + wave * 64) * 16]);
    }
    barrier_raw();
    {
      i32x8 bv[2];
#pragma unroll
      for (int nt = 0; nt < 2; ++nt) {
        int rb = 16384 + (wn + (nt + 2) * 16 + l16) * 128 + p0 * 16;
        ((i32x4*)&bv[nt])[0] = *(const i32x4*)&lds[cur][rb];
        ((i32x4*)&bv[nt])[1] = *(const i32x4*)&lds[cur][rb ^ 16];
      }
      __builtin_amdgcn_s_setprio(1);
#pragma unroll
      for (int mt = 0; mt < 4; ++mt)
#pragma unroll
        for (int nt = 0; nt < 2; ++nt)
          acc[mt][nt + 2] = __builtin_amdgcn_mfma_scale_f32_16x16x128_f8f6f4(
              af[mt], bv[nt], acc[mt][nt + 2], 0, 0, 0, 127, 0, 127);
      __builtin_amdgcn_s_setprio(0);
    }
    barrier_raw();  // all waves done reading buf[cur] before tt+1 overwrites it
  }

  // epilogue: C/D layout shape-determined, same as 16x16x32 [m121-m128]
#pragma unroll
  for (int mt = 0; mt < 4; ++mt) {
#pragma unroll
    for (int nt = 0; nt < 4; ++nt) {
      int col = n0 + wn + nt * 16 + l16;
      float bv = bias[col];
#pragma unroll
      for (int r = 0; r < 4; ++r) {
        int row = m0 + wm + mt * 16 + quad * 4 + r;
        Cout[(size_t)row * N + col] = f2e4m3(acc[mt][nt][r] + bv);
      }
    }
  }
}

// ---------------- QK^T upper-triangle exp row-sums + diagonal (MX fp8) ----------------
//  - one mfma_scale 16x16x128 per 16x16 score tile (K=128 = whole head-dim)
//  - waves split by COLUMN (each wave: 32 cols x all 64 rows)
//  - chunk-XOR swizzle staged via pre-swizzled global source
//  - diagonal/masked logic peeled into the first j-tile only
//  - 2-phase double-buffered staging; 2-way j-split (grid.x = 32)
__global__ __launch_bounds__(256, 4) void qk_rowsum8(
    const unsigned char* __restrict__ q8, const unsigned char* __restrict__ k8,
    float* __restrict__ denomA, float* __restrict__ denomB,
    float* __restrict__ diag) {
  __shared__ unsigned char lK[2][128 * 128];  // 32 KB double-buffered
  __shared__ float redS[4][64];
  __shared__ float redD[4][64];
  const int t = threadIdx.x;
  const int lane = t & 63, wave = t >> 6;
  const int quad = lane >> 4, l16 = lane & 15;
  const int bh = blockIdx.y;
  const int b = bh >> 4, h = bh & 15;
  const int pair = blockIdx.x >> 1;       // 0..15 (work-balanced i-tile pair)
  const int half = blockIdx.x & 1;        // j-split: tiles with k%2==half
  const float C = 0.03187935771f;         // (1/sqrt(2048)) * log2(e)
  const f32x4 fz = {0.f, 0.f, 0.f, 0.f};

  // staging source offsets (swizzled): LDS chunk L holds global chunk (L&7)^(row&7)
  int soff[4];
#pragma unroll
  for (int c = 0; c < 4; ++c) {
    int L = c * 256 + t;
    int row = L >> 3, p = L & 7;
    soff[c] = row * QKN + ((p ^ (row & 7)) * 16);
  }
  // LDS read byte offsets: B-row r = wave*32 + nt*16 + l16, phys chunk (2q)^(l16&7)
  const int p0 = (2 * quad) ^ (l16 & 7);
  int bo[2];
#pragma unroll
  for (int nt = 0; nt < 2; ++nt)
    bo[nt] = (wave * 32 + nt * 16 + l16) * 128 + p0 * 16;

  const unsigned char* kbase = k8 + (size_t)(b * SS) * QKN + h * HDIM;

  for (int sub = 0; sub < 2; ++sub) {
    const int tile = (sub == 0) ? pair : 31 - pair;
    const int i0 = tile * 64;
    const int jbase = i0 & ~127;
    const int ntile = (SS - jbase) >> 7;

    // A fragments: Q rows i0 + mt*16 + l16, k-bytes quad*32 (held in regs)
    i32x8 af[4];
    {
      const unsigned char* qbase =
          q8 + (size_t)(b * SS + i0 + l16) * QKN + h * HDIM + quad * 32;
#pragma unroll
      for (int mt = 0; mt < 4; ++mt)
        af[mt] = *(const i32x8*)(qbase + (size_t)(mt * 16) * QKN);
    }

    float rowacc[4][4] = {};

    int kidx = half;
    if (kidx < ntile) {
      {  // prologue: stage first tile into buf 0
        const unsigned char* src = kbase + (size_t)(jbase + kidx * 128) * QKN;
#pragma unroll
        for (int c = 0; c < 4; ++c)
          GLOAD_LDS16(src + soff[c], &lK[0][(c * 256 + wave * 64) * 16]);
      }
      asm volatile("s_waitcnt vmcnt(0)" ::: "memory");
      __syncthreads();
      int cur = 0;
      for (; kidx < ntile; kidx += 2, cur ^= 1) {
        if (kidx + 2 < ntile) {  // issue next-tile stage before compute
          const unsigned char* src =
              kbase + (size_t)(jbase + (kidx + 2) * 128) * QKN;
#pragma unroll
          for (int c = 0; c < 4; ++c)
            GLOAD_LDS16(src + soff[c], &lK[cur ^ 1][(c * 256 + wave * 64) * 16]);
        }
        const unsigned char* lkc = lK[cur];
        const int j0 = jbase + kidx * 128;
        if (kidx == 0) {
          // diagonal/masked tile (always half 0's first tile)
          float dloc[4][4] = {};
#pragma unroll
          for (int nt = 0; nt < 2; ++nt) {
            i32x8 bf;
            ((i32x4*)&bf)[0] = *(const i32x4*)(lkc + bo[nt]);
            ((i32x4*)&bf)[1] = *(const i32x4*)(lkc + (bo[nt] ^ 16));
            f32x4 acc[4];
#pragma unroll
            for (int mt = 0; mt < 4; ++mt)
              acc[mt] = __builtin_amdgcn_mfma_scale_f32_16x16x128_f8f6f4(
                  af[mt], bf, fz, 0, 0, 0, 127, 0, 127);
            const int colg = j0 + wave * 32 + nt * 16 + l16;
#pragma unroll
            for (int mt = 0; mt < 4; ++mt)
#pragma unroll
              for (int r = 0; r < 4; ++r) {
                int rg = i0 + mt * 16 + quad * 4 + r;
                float e = (colg >= rg)
                              ? __builtin_amdgcn_exp2f(acc[mt][r] * C) : 0.f;
                rowacc[mt][r] += e;
                if (colg == rg) dloc[mt][r] = e;
              }
          }
          // reduce + stash diag immediately (frees dloc registers)
#pragma unroll
          for (int mt = 0; mt < 4; ++mt)
#pragma unroll
            for (int r = 0; r < 4; ++r) {
              float d = dloc[mt][r];
#pragma unroll
              for (int off = 1; off < 16; off <<= 1) d += __shfl_xor(d, off, 64);
              if (l16 == 0) redD[wave][mt * 16 + quad * 4 + r] = d;
            }
        } else {
          // unmasked: all cols > all rows
#pragma unroll
          for (int nt = 0; nt < 2; ++nt) {
            i32x8 bf;
            ((i32x4*)&bf)[0] = *(const i32x4*)(lkc + bo[nt]);
            ((i32x4*)&bf)[1] = *(const i32x4*)(lkc + (bo[nt] ^ 16));
            f32x4 acc[4];
#pragma unroll
            for (int mt = 0; mt < 4; ++mt)
              acc[mt] = __builtin_amdgcn_mfma_scale_f32_16x16x128_f8f6f4(
                  af[mt], bf, fz, 0, 0, 0, 127, 0, 127);
#pragma unroll
            for (int mt = 0; mt < 4; ++mt)
#pragma unroll
              for (int r = 0; r < 4; ++r)
                rowacc[mt][r] += __builtin_amdgcn_exp2f(acc[mt][r] * C);
          }
        }
        asm volatile("s_waitcnt vmcnt(0)" ::: "memory");
        __syncthreads();
      }
    }

    // cross-wave reduction (redS/redD reused across subs -> barrier first)
    __syncthreads();
#pragma unroll
    for (int mt = 0; mt < 4; ++mt)
#pragma unroll
      for (int r = 0; r < 4; ++r) {
        float s = rowacc[mt][r];
#pragma unroll
        for (int off = 1; off < 16; off <<= 1) s += __shfl_xor(s, off, 64);
        if (l16 == 0) redS[wave][mt * 16 + quad * 4 + r] = s;
      }
    __syncthreads();
    if (t < 64) {
      const int rg = i0 + t;
      float s = redS[0][t] + redS[1][t] + redS[2][t] + redS[3][t];
      if (half == 0) {
        denomA[bh * SS + rg] = (float)rg + s;
        diag[bh * SS + rg] = redD[0][t] + redD[1][t] + redD[2][t] + redD[3][t];
      } else {
        denomB[bh * SS + rg] = s;
      }
    }
  }
}

// ---------------- V prefix-scan, two-pass, 16B/lane ----------------
// v is a dedicated [MTOK][DD] bf16 buffer.
__global__ void scan_pass1(const __bf16* __restrict__ v0,
                           float* __restrict__ csum) {
  int blk = blockIdx.x;
  int bh = blk >> 4, c = blk & 15;
  int b = bh >> 4, h = bh & 15;
  int t = threadIdx.x;
  int rs = t >> 4, dg = t & 15;
  const unsigned short* base = (const unsigned short*)v0 +
      (size_t)(b * SS + c * 128 + rs * 8) * DD + h * HDIM + dg * 8;
  float s[8] = {0.f, 0.f, 0.f, 0.f, 0.f, 0.f, 0.f, 0.f};
#pragma unroll
  for (int i = 0; i < 8; ++i) {
    uint4 u = *(const uint4*)(base + (size_t)i * DD);
    const unsigned short* us = (const unsigned short*)&u;
#pragma unroll
    for (int j = 0; j < 8; ++j) s[j] += bf2f(us[j]);
  }
  __shared__ float red[16 * 128];
#pragma unroll
  for (int j = 0; j < 8; ++j) red[rs * 128 + dg * 8 + j] = s[j];
  __syncthreads();
  for (int st = 8; st >= 1; st >>= 1) {
    if (rs < st) {
#pragma unroll
      for (int j = 0; j < 8; ++j)
        red[rs * 128 + dg * 8 + j] += red[(rs + st) * 128 + dg * 8 + j];
    }
    __syncthreads();
  }
  if (rs == 0) {
#pragma unroll
    for (int j = 0; j < 8; ++j)
      csum[(size_t)blk * 128 + dg * 8 + j] = red[dg * 8 + j];
  }
}

__global__ void scan_pass2(const __bf16* __restrict__ v0,
                           const float* __restrict__ csum,
                           const float* __restrict__ denomA,
                           const float* __restrict__ denomB,
                           const float* __restrict__ diag,
                           unsigned short* __restrict__ ctx) {
  int blk = blockIdx.x;
  int bh = blk >> 4, c = blk & 15;
  int b = bh >> 4, h = bh & 15;
  int t = threadIdx.x;
  int rs = t >> 4, dg = t & 15;
  const unsigned short* vbase = (const unsigned short*)v0 +
      (size_t)(b * SS + c * 128 + rs * 8) * DD + h * HDIM + dg * 8;
  float vrow[8][8];
  float ls[8] = {0.f, 0.f, 0.f, 0.f, 0.f, 0.f, 0.f, 0.f};
#pragma unroll
  for (int i = 0; i < 8; ++i) {
    uint4 u = *(const uint4*)(vbase + (size_t)i * DD);
    const unsigned short* us = (const unsigned short*)&u;
#pragma unroll
    for (int j = 0; j < 8; ++j) {
      vrow[i][j] = bf2f(us[j]);
      ls[j] += vrow[i][j];
    }
  }
  __shared__ float red[16 * 128];
#pragma unroll
  for (int j = 0; j < 8; ++j) red[rs * 128 + dg * 8 + j] = ls[j];
  __syncthreads();

  float pre[8] = {0.f, 0.f, 0.f, 0.f, 0.f, 0.f, 0.f, 0.f};
  for (int cc = 0; cc < c; ++cc) {
    const float* cp = csum + (size_t)(bh * 16 + cc) * 128 + dg * 8;
#pragma unroll
    for (int j = 0; j < 8; ++j) pre[j] += cp[j];
  }
  for (int ss2 = 0; ss2 < rs; ++ss2) {
#pragma unroll
    for (int j = 0; j < 8; ++j) pre[j] += red[ss2 * 128 + dg * 8 + j];
  }

  int row0 = c * 128 + rs * 8;
  unsigned short* obase =
      ctx + (size_t)(b * SS + row0) * DD + h * HDIM + dg * 8;
  const float* dnA = denomA + bh * SS + row0;
  const float* dnB = denomB + bh * SS + row0;
  const float* dgp = diag + bh * SS + row0;
#pragma unroll
  for (int i = 0; i < 8; ++i) {
    float inv = 1.0f / (dnA[i] + dnB[i]);
    float dv = dgp[i];
    unsigned short o[8];
#pragma unroll
    for (int j = 0; j < 8; ++j) {
      float val = (pre[j] + dv * vrow[i][j]) * inv;
      o[j] = f2bf(val);
      pre[j] += vrow[i][j];
    }
    *(uint4*)(obase + (size_t)i * DD) = *(const uint4*)o;
  }
}

extern "C" void kernel_launch(void* const* d_in, const int* in_sizes, int n_in,
                              void* d_out, int out_size, void* d_ws, size_t ws_size,
                              hipStream_t stream) {
  (void)in_sizes; (void)n_in; (void)out_size; (void)ws_size;
  const float* x    = (const float*)d_in[0];
  const float* wq_w = (const float*)d_in[1];
  const float* wq_b = (const float*)d_in[2];
  const float* wk_w = (const float*)d_in[3];
  const float* wk_b = (const float*)d_in[4];
  const float* wv_w = (const float*)d_in[5];
  const float* wv_b = (const float*)d_in[6];
  const float* wo_w = (const float*)d_in[7];
  const float* wo_b = (const float*)d_in[8];

  char* ws = (char*)d_ws;
  size_t off = 0;
  auto alloc = [&](size_t bytes) {
    char* p = ws + off;
    off += (bytes + 255) & ~(size_t)255;
    return p;
  };
  unsigned short* xb   = (unsigned short*)alloc((size_t)MTOK * DD * 2);    // 16 MB
  unsigned char*  x8   = (unsigned char*)alloc((size_t)MTOK * DD);         // 8 MB
  unsigned char*  wqk8 = (unsigned char*)alloc((size_t)2 * DD * DD);       // 8 MB
  unsigned short* wvo  = (unsigned short*)alloc((size_t)2 * DD * DD * 2);  // 16 MB (wv | wo)
  unsigned char*  qk8  = (unsigned char*)alloc((size_t)MTOK * QKN);        // 16 MB
  unsigned short* v    = (unsigned short*)alloc((size_t)MTOK * DD * 2);    // 16 MB
  unsigned short* ctx  = (unsigned short*)alloc((size_t)MTOK * DD * 2);    // 16 MB
  float* biasqk = (float*)alloc((size_t)2 * DD * 4);
  float* denomA = (float*)alloc((size_t)BHH * SS * 4);
  float* denomB = (float*)alloc((size_t)BHH * SS * 4);
  float* diag   = (float*)alloc((size_t)BHH * SS * 4);
  float* csum   = (float*)alloc((size_t)BHH * NCHUNK * 128 * 4);

  // 1) converts (x-convert + fused weight/bias converts)
  {
    int n4 = MTOK * DD / 4;
    cvt_x_dual<<<n4 / 256, 256, 0, stream>>>(x, xb, (unsigned int*)x8, n4);
    cvt_w_all<<<16400, 256, 0, stream>>>(wq_w, wk_w, wv_w, wo_w, wq_b, wk_b,
                                         (unsigned int*)wqk8, wvo, biasqk);
  }

  // 2) QK projection, MX-fp8 (2 blocks/CU + counted vmcnt, n-fast grid):
  //    [4096,2048] x [4096,2048]^T -> qk8 [4096][4096] e4m3
  gemm_qk8<<<dim3(QKN / 128, MTOK / 128), 256, 0, stream>>>(
      x8, wqk8, biasqk, qk8, MTOK, QKN, DD);

  // 3) V projection in bf16 -> v [4096][2048]  (128^2, 2 blocks/CU, counted vmcnt)
  gemm_bt8<true><<<dim3(DD / 128, MTOK / 128), 256, 0, stream>>>(
      (const __bf16*)xb, (const __bf16*)wvo, wv_b, v, MTOK, DD, DD);

  // 4) denominators + diagonal exps (MX fp8 MFMA, paired i-tiles, 2-way j-split)
  qk_rowsum8<<<dim3(32, BHH), 256, 0, stream>>>(
      qk8,            // q at col 0
      qk8 + DD,       // k at col 2048
      denomA, denomB, diag);

  // 5) V scan -> ctx
  scan_pass1<<<BHH * NCHUNK, 256, 0, stream>>>((const __bf16*)v, csum);
  scan_pass2<<<BHH * NCHUNK, 256, 0, stream>>>((const __bf16*)v, csum,
                                               denomA, denomB, diag, ctx);

  // 6) output projection: [4096,2048] x [2048,2048]^T -> d_out fp32
  gemm_bt8<false><<<dim3(DD / 128, MTOK / 128), 256, 0, stream>>>(
      (const __bf16*)ctx, (const __bf16*)(wvo + (size_t)DD * DD), wo_b,
      d_out, MTOK, DD, DD);
}